// Round 16
// baseline (405.456 us; speedup 1.0000x reference)
//
#include <hip/hip_runtime.h>

#define BATCH 1024
#define SEQ   144
#define DIM   192
#define NH    6
#define HD    32
#define SCALE 0.17677669529663687f   // 1/sqrt(32)

typedef __bf16 bf16x8 __attribute__((ext_vector_type(8)));
typedef __bf16 bf16x4 __attribute__((ext_vector_type(4)));
typedef float  f32x4  __attribute__((ext_vector_type(4)));

// LDS-only barrier (proven R9): orders ds_write->ds_read without draining vmcnt.
__device__ __forceinline__ void lds_barrier() {
    __builtin_amdgcn_sched_barrier(0);
    asm volatile("s_waitcnt lgkmcnt(0)" ::: "memory");
    __builtin_amdgcn_s_barrier();
    __builtin_amdgcn_sched_barrier(0);
}

// ---- workspace layout (bytes) ----
#define WS_W1T   0          // bf16 [576][192]  w1t[c][k] = w1[k][c] (*SCALE for c<192)
#define WS_W2T   221184     // bf16 [192][192]  w2t[n][k] = w2[k][n]
#define WS_B1S   294912     // f32  [576]       b1 (*SCALE for c<192)
#define WS_BM    297216     // bf16 [6][144][144]  bm[h][query][key] = bias + mask
#define WS_QF    546048     // bf16 [1024*6][144][32]  q ; aliased as opre after read
#define WS_KF    57169152   // bf16 [1024*6][144][32]  k
#define WS_VT    113792256  // bf16 [1024*6][32][144]  v^T
// total need 170415360 B (confirmed available in round 6)

#define BH_STRIDE 4608      // 144*32 elems per (b,h)

// ---------------------------------------------------------------------------
__global__ __launch_bounds__(256) void k_prep(
        const float* __restrict__ w1, const float* __restrict__ w2,
        const float* __restrict__ b1, const float* __restrict__ bt,
        const int* __restrict__ pidx, const int* __restrict__ mask,
        char* __restrict__ ws) {
    __bf16* w1t = (__bf16*)(ws + WS_W1T);
    __bf16* w2t = (__bf16*)(ws + WS_W2T);
    float*  b1s = (float*)(ws + WS_B1S);
    __bf16* bm  = (__bf16*)(ws + WS_BM);
    const int blk = blockIdx.x, t = threadIdx.x;
    if (blk < 432) {
        int idx = blk * 256 + t;
        int k = idx / 576, c = idx % 576;
        float v = w1[idx] * (c < 192 ? SCALE : 1.0f);
        w1t[c * 192 + k] = (__bf16)v;
    } else if (blk < 576) {
        int idx = (blk - 432) * 256 + t;
        int k = idx / 192, n = idx % 192;
        w2t[n * 192 + k] = (__bf16)w2[idx];
    } else if (blk < 657) {
        int idx = (blk - 576) * 256 + t;   // idx = query*144 + key
        int p = pidx[idx];
        float add = (mask[idx] == 0) ? -1e9f : 0.0f;
#pragma unroll
        for (int h = 0; h < NH; ++h)
            bm[h * 20736 + idx] = (__bf16)(bt[p * NH + h] + add);
    } else {
        for (int c = t; c < 576; c += 256)
            b1s[c] = b1[c] * (c < 192 ? SCALE : 1.0f);
    }
}

// ---------------------------------------------------------------------------
// QKV GEMM, BARRIER-FREE: 4 independent waves per block; wave owns 48 cols of
// group cg (block-wide); A-frags loaded DIRECTLY per-lane from global (each
// row read once per wave; trio XCD-co-located so X is L2-hot). Full-tile raw
// prefetch hides load latency under the 18-MFMA chain. q/k epilogue restaged
// through wave-private LDS (wave-internal DS ordering, NO barrier anywhere).
// LDS 7168 B; VGPR cap 168 via (256,3) -> 12 waves/CU, zero convoy.
// ---------------------------------------------------------------------------
__global__ __launch_bounds__(256, 3) void k_qkv(
        const float* __restrict__ x, char* __restrict__ ws) {
    const __bf16* w1t = (const __bf16*)(ws + WS_W1T);
    const float*  b1s = (const float*)(ws + WS_B1S);
    __bf16* qf  = (__bf16*)(ws + WS_QF);
    __bf16* kf  = (__bf16*)(ws + WS_KF);
    __bf16* vtf = (__bf16*)(ws + WS_VT);

    __shared__ __bf16 Stg[4][16 * 56];      // 7168 B: q/k waves' restage

    const int tid  = threadIdx.x;
    const int w    = tid >> 6;
    const int lane = tid & 63;
    const int lr   = lane & 15;
    const int lg   = lane >> 4;

    // XCD co-location (R13-proven): trio (b, cg=0..2) on one XCD, 8 slots apart
    const int phys = blockIdx.x;             // 3072 = 8 xcd * 384 slots
    const int logical = (phys & 7) * 384 + (phys >> 3);
    const int b  = logical / 3;
    const int cg = logical % 3;              // 0=q, 1=k, 2=v (whole block)
    const int wp = w;                        // wave's 48-col slice
    const f32x4 zf = {0.f, 0.f, 0.f, 0.f};

    // persistent B-frags + bias for this wave's 48 cols
    bf16x8 bW[3][6];
    float bcol[3];
#pragma unroll
    for (int i = 0; i < 3; ++i) {
        int col = cg * 192 + (wp * 3 + i) * 16 + lr;
        bcol[i] = b1s[col];
#pragma unroll
        for (int kk = 0; kk < 6; ++kk)
            bW[i][kk] = *(const bf16x8*)(w1t + (col * 192 + kk * 32 + lg * 8));
    }

    __bf16* qk_dst = (cg == 0) ? qf : kf;
    __bf16* stg = Stg[w];

    // per-lane A-row base: row lr (+16t), cols lg*8 (+32kk)
    const float* xr0 = x + ((size_t)b * SEQ + lr) * DIM + lg * 8;

    // prologue: raw-load tile 0
    f32x4 nu[6], nv[6];
#pragma unroll
    for (int kk = 0; kk < 6; ++kk) {
        nu[kk] = *(const f32x4*)(xr0 + kk * 32);
        nv[kk] = *(const f32x4*)(xr0 + kk * 32 + 4);
    }

#pragma unroll 1
    for (int t = 0; t < 9; ++t) {
        // convert current tile to A-frags
        bf16x8 aX[6];
#pragma unroll
        for (int kk = 0; kk < 6; ++kk) {
            f32x4 u = nu[kk], v = nv[kk];
            bf16x8 tt;
            tt[0]=(__bf16)u[0]; tt[1]=(__bf16)u[1]; tt[2]=(__bf16)u[2]; tt[3]=(__bf16)u[3];
            tt[4]=(__bf16)v[0]; tt[5]=(__bf16)v[1]; tt[6]=(__bf16)v[2]; tt[7]=(__bf16)v[3];
            aX[kk] = tt;
        }
        // issue next tile's raw loads (hide under MFMAs)
        if (t < 8) {
            const float* xr = xr0 + (size_t)(t + 1) * 16 * DIM;
#pragma unroll
            for (int kk = 0; kk < 6; ++kk) {
                nu[kk] = *(const f32x4*)(xr + kk * 32);
                nv[kk] = *(const f32x4*)(xr + kk * 32 + 4);
            }
        }

        f32x4 acc[3];
#pragma unroll
        for (int i = 0; i < 3; ++i) acc[i] = zf;
#pragma unroll
        for (int kk = 0; kk < 6; ++kk)
#pragma unroll
            for (int i = 0; i < 3; ++i)
                acc[i] = __builtin_amdgcn_mfma_f32_16x16x32_bf16(aX[kk], bW[i][kk], acc[i], 0, 0, 0);

        // ---- epilogue
        if (cg < 2) {
            // restage to wave-private LDS [16 m][56] (+bias, bf16)
#pragma unroll
            for (int i = 0; i < 3; ++i)
#pragma unroll
                for (int r = 0; r < 4; ++r)
                    stg[(lg * 4 + r) * 56 + i * 16 + lr] = (__bf16)(acc[i][r] + bcol[i]);
            // wave-internal readback (same-wave DS ordering) + 16B stores
#pragma unroll
            for (int rep = 0; rep < 2; ++rep) {
                int c = lane + rep * 64;
                if (rep == 0 || lane < 32) {
                    int m = c / 6, c8 = c % 6;
                    bf16x8 v = *(bf16x8*)&stg[m * 56 + c8 * 8];
                    int j2 = wp * 48 + c8 * 8;
                    int h = j2 >> 5, j = j2 & 31;
                    size_t bh = (size_t)b * NH + h;
                    *(bf16x8*)&qk_dst[bh * BH_STRIDE + (size_t)(t * 16 + m) * HD + j] = v;
                }
            }
        } else {
            const int m = t * 16 + lg * 4;
#pragma unroll
            for (int i = 0; i < 3; ++i) {
                int j2 = (wp * 3 + i) * 16 + lr;
                int h = j2 >> 5, j = j2 & 31;
                size_t bh = (size_t)b * NH + h;
                bf16x4 pk;
#pragma unroll
                for (int r = 0; r < 4; ++r) pk[r] = (__bf16)(acc[i][r] + bcol[i]);
                *(bf16x4*)&vtf[bh * BH_STRIDE + (size_t)j * SEQ + m] = pk;
            }
        }
    }
}

// ---------------------------------------------------------------------------
// Attention-only per (b,h) (R12-proven): K,V cooperatively staged, Q per-lane
// direct, bias L2, ONE barrier, R9 P2/softmax/P3. LDS 32768 B.
// ---------------------------------------------------------------------------
__global__ __launch_bounds__(576, 2) void k_attn3(char* __restrict__ ws) {
    const __bf16* bmB = (const __bf16*)(ws + WS_BM);
    const __bf16* qf  = (const __bf16*)(ws + WS_QF);
    const __bf16* kf  = (const __bf16*)(ws + WS_KF);
    const __bf16* vtf = (const __bf16*)(ws + WS_VT);
    __bf16* opre = (__bf16*)(ws + WS_QF);   // alias: own slice, read-then-write

    __shared__ char smem[32768];
    __bf16* Ks  = (__bf16*)smem;             // [144][40]  11520 B
    __bf16* Vt  = (__bf16*)(smem + 11520);   // [32][152]   9728 B
    __bf16* Pws = (__bf16*)(smem + 21248);   // 9 x [16][40] wave-private

    const int bx = blockIdx.x;               // 6144 = 6 h-groups x 1024 b
    const int h  = bx >> 10;
    const int b  = bx & 1023;
    const size_t bh = (size_t)(b * NH + h);

    const int tid  = threadIdx.x;
    const int w    = tid >> 6;
    const int lane = tid & 63;
    const int lr   = lane & 15;
    const int lg   = lane >> 4;
    const int m0   = w * 16;
    const f32x4 zf = {0.f, 0.f, 0.f, 0.f};
    const bf16x8 zb = {(__bf16)0.f,(__bf16)0.f,(__bf16)0.f,(__bf16)0.f,
                       (__bf16)0.f,(__bf16)0.f,(__bf16)0.f,(__bf16)0.f};

    // ---- issue all global loads up front
    bf16x8 kch = *(const bf16x8*)(kf  + bh * BH_STRIDE + (size_t)tid * 8);
    bf16x8 vch = *(const bf16x8*)(vtf + bh * BH_STRIDE + (size_t)tid * 8);
    bf16x8 qF  = *(const bf16x8*)(qf  + bh * BH_STRIDE + (size_t)(m0 + lr) * HD + lg * 8);
    bf16x4 bb[9];
    {
        const __bf16* bmh = bmB + h * 20736 + (m0 + lr) * SEQ;
#pragma unroll
        for (int i = 0; i < 9; ++i) bb[i] = *(const bf16x4*)&bmh[i * 16 + lg * 4];
    }

    // ---- stage to LDS
    *(bf16x8*)&Ks[(tid >> 2) * 40 + (tid & 3) * 8] = kch;
    {
        int vr = tid / 18, vc = tid % 18;
        *(bf16x8*)&Vt[vr * 152 + vc * 8] = vch;
    }
    lds_barrier();   // the ONE barrier

    // ---- P2: S^T = mfma(K,Q); +bias; in-register softmax
    f32x4 st[9];
#pragma unroll
    for (int i = 0; i < 9; ++i) {
        bf16x8 aF = *(bf16x8*)&Ks[(i * 16 + lr) * 40 + lg * 8];
        st[i] = __builtin_amdgcn_mfma_f32_16x16x32_bf16(aF, qF, zf, 0, 0, 0);
    }
    float mx = -3.0e38f;
#pragma unroll
    for (int i = 0; i < 9; ++i)
#pragma unroll
        for (int r = 0; r < 4; ++r) {
            st[i][r] += (float)bb[i][r];
            mx = fmaxf(mx, st[i][r]);
        }
    mx = fmaxf(mx, __shfl_xor(mx, 16));
    mx = fmaxf(mx, __shfl_xor(mx, 32));
    float sum = 0.f;
#pragma unroll
    for (int i = 0; i < 9; ++i)
#pragma unroll
        for (int r = 0; r < 4; ++r) {
            float e = __expf(st[i][r] - mx);
            st[i][r] = e;
            sum += e;
        }
    sum += __shfl_xor(sum, 16);
    sum += __shfl_xor(sum, 32);
    float inv = 1.f / sum;
#pragma unroll
    for (int i = 0; i < 9; ++i)
#pragma unroll
        for (int r = 0; r < 4; ++r) st[i][r] *= inv;

    // ---- P3: O = P @ V via per-wave P scratch
    __bf16* Pw = Pws + w * 640;    // [16][40]
    f32x4 o0 = zf, o1 = zf;
#pragma unroll
    for (int s = 0; s < 4; ++s) {
#pragma unroll
        for (int d = 0; d < 2; ++d) {
            int ii = 2 * s + d;
            bf16x4 pk;
#pragma unroll
            for (int r = 0; r < 4; ++r) pk[r] = (__bf16)st[ii][r];
            *(bf16x4*)&Pw[lr * 40 + d * 16 + lg * 4] = pk;
        }
        bf16x8 aP  = *(bf16x8*)&Pw[lr * 40 + lg * 8];
        bf16x8 v0F = *(bf16x8*)&Vt[lr * 152 + s * 32 + lg * 8];
        bf16x8 v1F = *(bf16x8*)&Vt[(16 + lr) * 152 + s * 32 + lg * 8];
        o0 = __builtin_amdgcn_mfma_f32_16x16x32_bf16(aP, v0F, o0, 0, 0, 0);
        o1 = __builtin_amdgcn_mfma_f32_16x16x32_bf16(aP, v1F, o1, 0, 0, 0);
    }
    {   // tail keys 128..143: lanes lg>=2 supply zeros
        bf16x4 pk;
#pragma unroll
        for (int r = 0; r < 4; ++r) pk[r] = (__bf16)st[8][r];
        *(bf16x4*)&Pw[lr * 40 + lg * 4] = pk;
        bf16x8 aP = zb, v0F = zb, v1F = zb;
        if (lg < 2) {
            aP  = *(bf16x8*)&Pw[lr * 40 + lg * 8];
            v0F = *(bf16x8*)&Vt[lr * 152 + 128 + lg * 8];
            v1F = *(bf16x8*)&Vt[(16 + lr) * 152 + 128 + lg * 8];
        }
        o0 = __builtin_amdgcn_mfma_f32_16x16x32_bf16(aP, v0F, o0, 0, 0, 0);
        o1 = __builtin_amdgcn_mfma_f32_16x16x32_bf16(aP, v1F, o1, 0, 0, 0);
    }

    // ---- O restage (coalesce) + store to opre (h-major, aliases own q slice)
#pragma unroll
    for (int r = 0; r < 4; ++r) {
        Pw[(lg * 4 + r) * 40 + lr]      = (__bf16)o0[r];
        Pw[(lg * 4 + r) * 40 + 16 + lr] = (__bf16)o1[r];
    }
    {
        int row = lane >> 2, c = lane & 3;
        bf16x8 ov = *(bf16x8*)&Pw[row * 40 + c * 8];
        *(bf16x8*)&opre[bh * BH_STRIDE + (size_t)(m0 + row) * HD + c * 8] = ov;
    }
}

// ---------------------------------------------------------------------------
// Out-projection (R12-proven): register-B, h-major gather, dbuf staging.
// ---------------------------------------------------------------------------
__global__ __launch_bounds__(256, 3) void k_proj(
        const char* __restrict__ ws, const float* __restrict__ b2,
        float* __restrict__ out) {
    const __bf16* opre = (const __bf16*)(ws + WS_QF);
    const __bf16* w2t  = (const __bf16*)(ws + WS_W2T);
    __shared__ __bf16 As[2][16 * 200];

    const int tid = threadIdx.x;
    const int w = tid >> 6, lr = tid & 15, lg = (tid & 63) >> 4;
    const int b = blockIdx.x;
    const f32x4 zf = {0.f, 0.f, 0.f, 0.f};

    bf16x8 bW[3][6];
    float bcol[3];
#pragma unroll
    for (int i = 0; i < 3; ++i) {
        int col = (w * 3 + i) * 16 + lr;
        bcol[i] = b2[col];
#pragma unroll
        for (int kk = 0; kk < 6; ++kk)
            bW[i][kk] = *(const bf16x8*)(w2t + (col * 192 + kk * 32 + lg * 8));
    }

    auto src_of = [&](int t, int c) -> const __bf16* {
        int lrow = c / 24, c8 = c % 24;
        int h = c8 >> 2, col32 = (c8 & 3) * 8;
        return opre + ((size_t)(b * NH + h)) * BH_STRIDE
                    + (size_t)(t * 16 + lrow) * HD + col32;
    };
    auto dst_of = [&](int buf, int c) -> __bf16* {
        int lrow = c / 24, c8 = c % 24;
        return &As[buf][lrow * 200 + c8 * 8];
    };

    {
        *(bf16x8*)dst_of(0, tid) = *(const bf16x8*)src_of(0, tid);
        if (tid < 128)
            *(bf16x8*)dst_of(0, tid + 256) = *(const bf16x8*)src_of(0, tid + 256);
    }

    for (int t = 0; t < 9; ++t) {
        bf16x8 n0, n1;
        if (t < 8) {
            n0 = *(const bf16x8*)src_of(t + 1, tid);
            if (tid < 128) n1 = *(const bf16x8*)src_of(t + 1, tid + 256);
        }
        lds_barrier();
        const __bf16* A = As[t & 1];
        f32x4 acc[3];
#pragma unroll
        for (int i = 0; i < 3; ++i) acc[i] = zf;
#pragma unroll
        for (int kk = 0; kk < 6; ++kk) {
            bf16x8 aF = *(const bf16x8*)&A[lr * 200 + kk * 32 + lg * 8];
#pragma unroll
            for (int i = 0; i < 3; ++i)
                acc[i] = __builtin_amdgcn_mfma_f32_16x16x32_bf16(aF, bW[i][kk], acc[i], 0, 0, 0);
        }
        size_t row0 = (size_t)b * SEQ + t * 16;
#pragma unroll
        for (int i = 0; i < 3; ++i) {
            int col = (w * 3 + i) * 16 + lr;
#pragma unroll
            for (int r = 0; r < 4; ++r)
                out[(row0 + lg * 4 + r) * DIM + col] = acc[i][r] + bcol[i];
        }
        if (t < 8) {
            *(bf16x8*)dst_of((t + 1) & 1, tid) = n0;
            if (tid < 128) *(bf16x8*)dst_of((t + 1) & 1, tid + 256) = n1;
        }
    }
}

// ---------------------------------------------------------------------------
extern "C" void kernel_launch(void* const* d_in, const int* in_sizes, int n_in,
                              void* d_out, int out_size, void* d_ws, size_t ws_size,
                              hipStream_t stream) {
    const float* x    = (const float*)d_in[0];
    const float* w1   = (const float*)d_in[1];
    const float* b1   = (const float*)d_in[2];
    const float* w2   = (const float*)d_in[3];
    const float* b2   = (const float*)d_in[4];
    const float* bt   = (const float*)d_in[5];
    const int*   pidx = (const int*)d_in[6];
    const int*   mask = (const int*)d_in[7];
    float* out = (float*)d_out;
    char*  ws  = (char*)d_ws;

    k_prep<<<658, 256, 0, stream>>>(w1, w2, b1, bt, pidx, mask, ws);
    k_qkv<<<3072, 256, 0, stream>>>(x, ws);
    k_attn3<<<BATCH * NH, 576, 0, stream>>>(ws);
    k_proj<<<BATCH, 256, 0, stream>>>(ws, b2, out);
}

// Round 17
// 241.762 us; speedup vs baseline: 1.6771x; 1.6771x over previous
//
#include <hip/hip_runtime.h>

#define BATCH 1024
#define SEQ   144
#define DIM   192
#define NH    6
#define HD    32
#define SCALE 0.17677669529663687f   // 1/sqrt(32)

typedef __bf16 bf16x8 __attribute__((ext_vector_type(8)));
typedef __bf16 bf16x4 __attribute__((ext_vector_type(4)));
typedef float  f32x4  __attribute__((ext_vector_type(4)));

// LDS-only barrier (proven R9): orders ds_write->ds_read without draining vmcnt.
__device__ __forceinline__ void lds_barrier() {
    __builtin_amdgcn_sched_barrier(0);
    asm volatile("s_waitcnt lgkmcnt(0)" ::: "memory");
    __builtin_amdgcn_s_barrier();
    __builtin_amdgcn_sched_barrier(0);
}

// ---- workspace layout (bytes) ----
#define WS_W1T   0          // bf16 [576][192]  w1t[c][k] = w1[k][c] (*SCALE for c<192)
#define WS_W2T   221184     // bf16 [192][192]  w2t[n][k] = w2[k][n]
#define WS_B1S   294912     // f32  [576]       b1 (*SCALE for c<192)
#define WS_BM    297216     // bf16 [6][144][144]  bm[h][query][key] = bias + mask
#define WS_QF    546048     // bf16 [1024*6][144][32]  q
#define WS_KF    57169152   // bf16 [1024*6][144][32]  k
#define WS_VT    113792256  // bf16 [1024*6][32][144]  v^T
// total need 170415360 B (confirmed available in round 6)

#define BH_STRIDE 4608      // 144*32 elems per (b,h)

// ---------------------------------------------------------------------------
__global__ __launch_bounds__(256) void k_prep(
        const float* __restrict__ w1, const float* __restrict__ w2,
        const float* __restrict__ b1, const float* __restrict__ bt,
        const int* __restrict__ pidx, const int* __restrict__ mask,
        char* __restrict__ ws) {
    __bf16* w1t = (__bf16*)(ws + WS_W1T);
    __bf16* w2t = (__bf16*)(ws + WS_W2T);
    float*  b1s = (float*)(ws + WS_B1S);
    __bf16* bm  = (__bf16*)(ws + WS_BM);
    const int blk = blockIdx.x, t = threadIdx.x;
    if (blk < 432) {
        int idx = blk * 256 + t;
        int k = idx / 576, c = idx % 576;
        float v = w1[idx] * (c < 192 ? SCALE : 1.0f);
        w1t[c * 192 + k] = (__bf16)v;
    } else if (blk < 576) {
        int idx = (blk - 432) * 256 + t;
        int k = idx / 192, n = idx % 192;
        w2t[n * 192 + k] = (__bf16)w2[idx];
    } else if (blk < 657) {
        int idx = (blk - 576) * 256 + t;   // idx = query*144 + key
        int p = pidx[idx];
        float add = (mask[idx] == 0) ? -1e9f : 0.0f;
#pragma unroll
        for (int h = 0; h < NH; ++h)
            bm[h * 20736 + idx] = (__bf16)(bt[p * NH + h] + add);
    } else {
        for (int c = t; c < 576; c += 256)
            b1s[c] = b1[c] * (c < 192 ? SCALE : 1.0f);
    }
}

// ---------------------------------------------------------------------------
// QKV GEMM — EXACT R14-proven version (107 us): register-B pattern, XCD trio
// co-location, dbuf LDS A-staging, q/k epilogue via wave-private LDS restage.
// ---------------------------------------------------------------------------
__global__ __launch_bounds__(256, 3) void k_qkv(
        const float* __restrict__ x, char* __restrict__ ws) {
    const __bf16* w1t = (const __bf16*)(ws + WS_W1T);
    const float*  b1s = (const float*)(ws + WS_B1S);
    __bf16* qf  = (__bf16*)(ws + WS_QF);
    __bf16* kf  = (__bf16*)(ws + WS_KF);
    __bf16* vtf = (__bf16*)(ws + WS_VT);

    __shared__ __bf16 As[2][16 * 200];      // 12800 B
    __shared__ __bf16 Stg[4][16 * 56];      // 7168 B: per-wave q/k restage

    const int tid = threadIdx.x;
    const int w = tid >> 6, lane = tid & 63, lr = tid & 15, lg = (tid & 63) >> 4;

    const int phys = blockIdx.x;             // 3072 = 8 xcd * 384 slots
    const int logical = (phys & 7) * 384 + (phys >> 3);
    const int b  = logical / 3;
    const int cg = logical % 3;              // 0=q, 1=k, 2=v
    const f32x4 zf = {0.f, 0.f, 0.f, 0.f};

    bf16x8 bW[3][6];
    float bcol[3];
#pragma unroll
    for (int i = 0; i < 3; ++i) {
        int col = cg * 192 + (w * 3 + i) * 16 + lr;
        bcol[i] = b1s[col];
#pragma unroll
        for (int kk = 0; kk < 6; ++kk)
            bW[i][kk] = *(const bf16x8*)(w1t + (col * 192 + kk * 32 + lg * 8));
    }

    __bf16* qk_dst = (cg == 0) ? qf : kf;
    __bf16* stg = Stg[w];

    const int c0 = tid;
    auto stage = [&](int t, int buf) {
        const float* src = x + ((size_t)b * SEQ + t * 16) * DIM;
#pragma unroll
        for (int j = 0; j < 3; ++j) {
            int c = c0 + j * 256;
            int row = c / 48, c4 = (c % 48) * 4;
            f32x4 v = *(const f32x4*)&src[row * DIM + c4];
            bf16x4 pk;
            pk[0] = (__bf16)v[0]; pk[1] = (__bf16)v[1];
            pk[2] = (__bf16)v[2]; pk[3] = (__bf16)v[3];
            *(bf16x4*)&As[buf][row * 200 + c4] = pk;
        }
    };

    stage(0, 0);

    for (int t = 0; t < 9; ++t) {
        f32x4 nxt[3];
        if (t < 8) {
            const float* src = x + ((size_t)b * SEQ + (t + 1) * 16) * DIM;
#pragma unroll
            for (int j = 0; j < 3; ++j) {
                int c = c0 + j * 256;
                int row = c / 48, c4 = (c % 48) * 4;
                nxt[j] = *(const f32x4*)&src[row * DIM + c4];
            }
        }
        lds_barrier();
        const __bf16* A = As[t & 1];
        f32x4 acc[3];
#pragma unroll
        for (int i = 0; i < 3; ++i) acc[i] = zf;
#pragma unroll
        for (int kk = 0; kk < 6; ++kk) {
            bf16x8 aF = *(const bf16x8*)&A[lr * 200 + kk * 32 + lg * 8];
#pragma unroll
            for (int i = 0; i < 3; ++i)
                acc[i] = __builtin_amdgcn_mfma_f32_16x16x32_bf16(aF, bW[i][kk], acc[i], 0, 0, 0);
        }

        if (cg < 2) {
#pragma unroll
            for (int i = 0; i < 3; ++i)
#pragma unroll
                for (int r = 0; r < 4; ++r)
                    stg[(lg * 4 + r) * 56 + i * 16 + lr] = (__bf16)(acc[i][r] + bcol[i]);
#pragma unroll
            for (int rep = 0; rep < 2; ++rep) {
                int c = lane + rep * 64;
                if (rep == 0 || lane < 32) {
                    int m = c / 6, c8 = c % 6;
                    bf16x8 v = *(bf16x8*)&stg[m * 56 + c8 * 8];
                    int j2 = w * 48 + c8 * 8;
                    int h = j2 >> 5, j = j2 & 31;
                    size_t bh = (size_t)b * NH + h;
                    *(bf16x8*)&qk_dst[bh * BH_STRIDE + (size_t)(t * 16 + m) * HD + j] = v;
                }
            }
        } else {
            const int m = t * 16 + lg * 4;
#pragma unroll
            for (int i = 0; i < 3; ++i) {
                int j2 = (w * 3 + i) * 16 + lr;
                int h = j2 >> 5, j = j2 & 31;
                size_t bh = (size_t)b * NH + h;
                bf16x4 pk;
#pragma unroll
                for (int r = 0; r < 4; ++r) pk[r] = (__bf16)(acc[i][r] + bcol[i]);
                *(bf16x4*)&vtf[bh * BH_STRIDE + (size_t)j * SEQ + m] = pk;
            }
        }

        if (t < 8) {
#pragma unroll
            for (int j = 0; j < 3; ++j) {
                int c = c0 + j * 256;
                int row = c / 48, c4 = (c % 48) * 4;
                f32x4 v = nxt[j];
                bf16x4 pk;
                pk[0] = (__bf16)v[0]; pk[1] = (__bf16)v[1];
                pk[2] = (__bf16)v[2]; pk[3] = (__bf16)v[3];
                *(bf16x4*)&As[(t + 1) & 1][row * 200 + c4] = pk;
            }
        }
    }
}

// ---------------------------------------------------------------------------
// FUSED attention + out-projection per b: loop h=0..5 with attn3's proven
// staging/P2/P3; O-strip lands in wave-private Pw (LDS) and is read back as
// the P4 A-fragment; P4 = R3-proven direct-L2 w2t B-frags in 2x6-col halves
// (24 transient VGPR); outacc[12] accumulates across heads; one fp32 write.
// Removes the opre round-trip (114 MB). LDS 32768 B; 2 lds_barriers per h.
// ---------------------------------------------------------------------------
__global__ __launch_bounds__(576, 3) void k_attnproj(
        const char* __restrict__ ws, const float* __restrict__ b2,
        float* __restrict__ out) {
    const __bf16* bmB = (const __bf16*)(ws + WS_BM);
    const __bf16* qf  = (const __bf16*)(ws + WS_QF);
    const __bf16* kf  = (const __bf16*)(ws + WS_KF);
    const __bf16* vtf = (const __bf16*)(ws + WS_VT);
    const __bf16* w2t = (const __bf16*)(ws + WS_W2T);

    __shared__ char smem[32768];
    __bf16* Ks  = (__bf16*)smem;             // [144][40]  11520 B
    __bf16* Vt  = (__bf16*)(smem + 11520);   // [32][152]   9728 B
    __bf16* Pws = (__bf16*)(smem + 21248);   // 9 x [16][40] wave-private

    const int b = blockIdx.x;

    const int tid  = threadIdx.x;
    const int w    = tid >> 6;
    const int lane = tid & 63;
    const int lr   = lane & 15;
    const int lg   = lane >> 4;
    const int m0   = w * 16;
    const f32x4 zf = {0.f, 0.f, 0.f, 0.f};
    const bf16x8 zb = {(__bf16)0.f,(__bf16)0.f,(__bf16)0.f,(__bf16)0.f,
                       (__bf16)0.f,(__bf16)0.f,(__bf16)0.f,(__bf16)0.f};

    __bf16* Pw = Pws + w * 640;    // [16][40] wave-private
    f32x4 outacc[12];
#pragma unroll
    for (int n = 0; n < 12; ++n) outacc[n] = zf;

#pragma unroll 1
    for (int h = 0; h < NH; ++h) {
        const size_t bh = (size_t)b * NH + h;

        // ---- issue global loads (fly across barrier A; lds_barrier is LDS-only)
        bf16x8 kch = *(const bf16x8*)(kf  + bh * BH_STRIDE + (size_t)tid * 8);
        bf16x8 vch = *(const bf16x8*)(vtf + bh * BH_STRIDE + (size_t)tid * 8);
        bf16x8 qF  = *(const bf16x8*)(qf  + bh * BH_STRIDE + (size_t)(m0 + lr) * HD + lg * 8);
        bf16x4 bb[9];
        {
            const __bf16* bmh = bmB + h * 20736 + (m0 + lr) * SEQ;
#pragma unroll
            for (int i = 0; i < 9; ++i) bb[i] = *(const bf16x4*)&bmh[i * 16 + lg * 4];
        }

        lds_barrier();   // barrier A: previous h's Ks/Vt reads complete

        // ---- stage to LDS
        *(bf16x8*)&Ks[(tid >> 2) * 40 + (tid & 3) * 8] = kch;
        {
            int vr = tid / 18, vc = tid % 18;
            *(bf16x8*)&Vt[vr * 152 + vc * 8] = vch;
        }
        lds_barrier();   // barrier B: Ks/Vt published

        // ---- P2: S^T = mfma(K,Q); +bias; in-register softmax (attn3-proven)
        f32x4 st[9];
#pragma unroll
        for (int i = 0; i < 9; ++i) {
            bf16x8 aF = *(bf16x8*)&Ks[(i * 16 + lr) * 40 + lg * 8];
            st[i] = __builtin_amdgcn_mfma_f32_16x16x32_bf16(aF, qF, zf, 0, 0, 0);
        }
        float mx = -3.0e38f;
#pragma unroll
        for (int i = 0; i < 9; ++i)
#pragma unroll
            for (int r = 0; r < 4; ++r) {
                st[i][r] += (float)bb[i][r];
                mx = fmaxf(mx, st[i][r]);
            }
        mx = fmaxf(mx, __shfl_xor(mx, 16));
        mx = fmaxf(mx, __shfl_xor(mx, 32));
        float sum = 0.f;
#pragma unroll
        for (int i = 0; i < 9; ++i)
#pragma unroll
            for (int r = 0; r < 4; ++r) {
                float e = __expf(st[i][r] - mx);
                st[i][r] = e;
                sum += e;
            }
        sum += __shfl_xor(sum, 16);
        sum += __shfl_xor(sum, 32);
        float inv = 1.f / sum;
#pragma unroll
        for (int i = 0; i < 9; ++i)
#pragma unroll
            for (int r = 0; r < 4; ++r) st[i][r] *= inv;

        // ---- P3: O = P @ V via per-wave P scratch (attn3-proven)
        f32x4 o0 = zf, o1 = zf;
#pragma unroll
        for (int s = 0; s < 4; ++s) {
#pragma unroll
            for (int d = 0; d < 2; ++d) {
                int ii = 2 * s + d;
                bf16x4 pk;
#pragma unroll
                for (int r = 0; r < 4; ++r) pk[r] = (__bf16)st[ii][r];
                *(bf16x4*)&Pw[lr * 40 + d * 16 + lg * 4] = pk;
            }
            bf16x8 aP  = *(bf16x8*)&Pw[lr * 40 + lg * 8];
            bf16x8 v0F = *(bf16x8*)&Vt[lr * 152 + s * 32 + lg * 8];
            bf16x8 v1F = *(bf16x8*)&Vt[(16 + lr) * 152 + s * 32 + lg * 8];
            o0 = __builtin_amdgcn_mfma_f32_16x16x32_bf16(aP, v0F, o0, 0, 0, 0);
            o1 = __builtin_amdgcn_mfma_f32_16x16x32_bf16(aP, v1F, o1, 0, 0, 0);
        }
        {   // tail keys 128..143: lanes lg>=2 supply zeros
            bf16x4 pk;
#pragma unroll
            for (int r = 0; r < 4; ++r) pk[r] = (__bf16)st[8][r];
            *(bf16x4*)&Pw[lr * 40 + lg * 4] = pk;
            bf16x8 aP = zb, v0F = zb, v1F = zb;
            if (lg < 2) {
                aP  = *(bf16x8*)&Pw[lr * 40 + lg * 8];
                v0F = *(bf16x8*)&Vt[lr * 152 + 128 + lg * 8];
                v1F = *(bf16x8*)&Vt[(16 + lr) * 152 + 128 + lg * 8];
            }
            o0 = __builtin_amdgcn_mfma_f32_16x16x32_bf16(aP, v0F, o0, 0, 0, 0);
            o1 = __builtin_amdgcn_mfma_f32_16x16x32_bf16(aP, v1F, o1, 0, 0, 0);
        }

        // ---- O strip -> Pw (wave-private; same-wave DS ordering, no barrier)
#pragma unroll
        for (int r = 0; r < 4; ++r) {
            Pw[(lg * 4 + r) * 40 + lr]      = (__bf16)o0[r];
            Pw[(lg * 4 + r) * 40 + 16 + lr] = (__bf16)o1[r];
        }

        // ---- P4: outacc += O_h @ W2_h  (R3-proven direct-L2 B-frags, 2 halves)
        {
            bf16x8 aO = *(bf16x8*)&Pw[lr * 40 + lg * 8];
#pragma unroll
            for (int half = 0; half < 2; ++half) {
                bf16x8 bW2[6];
#pragma unroll
                for (int q = 0; q < 6; ++q) {
                    int n = half * 6 + q;
                    bW2[q] = *(const bf16x8*)(w2t + ((n * 16 + lr) * 192 + h * 32 + lg * 8));
                }
#pragma unroll
                for (int q = 0; q < 6; ++q) {
                    int n = half * 6 + q;
                    outacc[n] = __builtin_amdgcn_mfma_f32_16x16x32_bf16(aO, bW2[q], outacc[n], 0, 0, 0);
                }
            }
        }
    }

    // ---- epilogue: + b2, fp32 store (R2-proven mapping)
#pragma unroll
    for (int n = 0; n < 12; ++n) {
        int col = n * 16 + lr;
        float bb2 = b2[col];
#pragma unroll
        for (int r = 0; r < 4; ++r)
            out[((size_t)b * SEQ + m0 + lg * 4 + r) * DIM + col] = outacc[n][r] + bb2;
    }
}

// ---------------------------------------------------------------------------
extern "C" void kernel_launch(void* const* d_in, const int* in_sizes, int n_in,
                              void* d_out, int out_size, void* d_ws, size_t ws_size,
                              hipStream_t stream) {
    const float* x    = (const float*)d_in[0];
    const float* w1   = (const float*)d_in[1];
    const float* b1   = (const float*)d_in[2];
    const float* w2   = (const float*)d_in[3];
    const float* b2   = (const float*)d_in[4];
    const float* bt   = (const float*)d_in[5];
    const int*   pidx = (const int*)d_in[6];
    const int*   mask = (const int*)d_in[7];
    float* out = (float*)d_out;
    char*  ws  = (char*)d_ws;

    k_prep<<<658, 256, 0, stream>>>(w1, w2, b1, bt, pidx, mask, ws);
    k_qkv<<<3072, 256, 0, stream>>>(x, ws);
    k_attnproj<<<BATCH, 576, 0, stream>>>(ws, b2, out);
}

// Round 18
// 191.448 us; speedup vs baseline: 2.1178x; 1.2628x over previous
//
#include <hip/hip_runtime.h>

#define BATCH 1024
#define SEQ   144
#define DIM   192
#define NH    6
#define HD    32
#define SCALE 0.17677669529663687f   // 1/sqrt(32)

typedef __bf16 bf16x8 __attribute__((ext_vector_type(8)));
typedef __bf16 bf16x4 __attribute__((ext_vector_type(4)));
typedef float  f32x4  __attribute__((ext_vector_type(4)));

// LDS-only barrier (proven R9): orders ds_write->ds_read without draining vmcnt.
__device__ __forceinline__ void lds_barrier() {
    __builtin_amdgcn_sched_barrier(0);
    asm volatile("s_waitcnt lgkmcnt(0)" ::: "memory");
    __builtin_amdgcn_s_barrier();
    __builtin_amdgcn_sched_barrier(0);
}

// ---- workspace layout (bytes) ----
#define WS_W1T   0          // bf16 [576][192]  w1t[c][k] = w1[k][c] (*SCALE for c<192)
#define WS_W2T   221184     // bf16 [192][192]  w2t[n][k] = w2[k][n]
#define WS_B1S   294912     // f32  [576]       b1 (*SCALE for c<192)
#define WS_BM    297216     // bf16 [6][144][144]  bm[h][query][key] = bias + mask
#define WS_QF    546048     // bf16 [1024*6][144][32]  q ; aliased as opre after read
#define WS_KF    57169152   // bf16 [1024*6][144][32]  k
#define WS_VT    113792256  // bf16 [1024*6][32][144]  v^T
// total need 170415360 B (confirmed available in round 6)

#define BH_STRIDE 4608      // 144*32 elems per (b,h)

// ---------------------------------------------------------------------------
__global__ __launch_bounds__(256) void k_prep(
        const float* __restrict__ w1, const float* __restrict__ w2,
        const float* __restrict__ b1, const float* __restrict__ bt,
        const int* __restrict__ pidx, const int* __restrict__ mask,
        char* __restrict__ ws) {
    __bf16* w1t = (__bf16*)(ws + WS_W1T);
    __bf16* w2t = (__bf16*)(ws + WS_W2T);
    float*  b1s = (float*)(ws + WS_B1S);
    __bf16* bm  = (__bf16*)(ws + WS_BM);
    const int blk = blockIdx.x, t = threadIdx.x;
    if (blk < 432) {
        int idx = blk * 256 + t;
        int k = idx / 576, c = idx % 576;
        float v = w1[idx] * (c < 192 ? SCALE : 1.0f);
        w1t[c * 192 + k] = (__bf16)v;
    } else if (blk < 576) {
        int idx = (blk - 432) * 256 + t;
        int k = idx / 192, n = idx % 192;
        w2t[n * 192 + k] = (__bf16)w2[idx];
    } else if (blk < 657) {
        int idx = (blk - 576) * 256 + t;   // idx = query*144 + key
        int p = pidx[idx];
        float add = (mask[idx] == 0) ? -1e9f : 0.0f;
#pragma unroll
        for (int h = 0; h < NH; ++h)
            bm[h * 20736 + idx] = (__bf16)(bt[p * NH + h] + add);
    } else {
        for (int c = t; c < 576; c += 256)
            b1s[c] = b1[c] * (c < 192 ? SCALE : 1.0f);
    }
}

// ---------------------------------------------------------------------------
// QKV GEMM (register-B pattern + XCD trio co-location, R13-proven on FETCH).
// q/k epilogue restaged through wave-private LDS -> bf16x8 coalesced stores
// (R14-proven: 119 -> 107 us). V path: bf16x4 stores to v^T.
// ---------------------------------------------------------------------------
__global__ __launch_bounds__(256, 3) void k_qkv(
        const float* __restrict__ x, char* __restrict__ ws) {
    const __bf16* w1t = (const __bf16*)(ws + WS_W1T);
    const float*  b1s = (const float*)(ws + WS_B1S);
    __bf16* qf  = (__bf16*)(ws + WS_QF);
    __bf16* kf  = (__bf16*)(ws + WS_KF);
    __bf16* vtf = (__bf16*)(ws + WS_VT);

    __shared__ __bf16 As[2][16 * 200];      // 12800 B
    __shared__ __bf16 Stg[4][16 * 56];      // 7168 B: per-wave q/k restage

    const int tid = threadIdx.x;
    const int w = tid >> 6, lane = tid & 63, lr = tid & 15, lg = (tid & 63) >> 4;

    // XCD co-location: trio (b, cg=0..2) on one XCD 8 slots apart.
    const int phys = blockIdx.x;             // 3072 = 8 xcd * 384 slots
    const int logical = (phys & 7) * 384 + (phys >> 3);
    const int b  = logical / 3;
    const int cg = logical % 3;              // 0=q, 1=k, 2=v
    const f32x4 zf = {0.f, 0.f, 0.f, 0.f};

    // persistent B-frags + bias for this wave's 48 cols of this group
    bf16x8 bW[3][6];
    float bcol[3];
#pragma unroll
    for (int i = 0; i < 3; ++i) {
        int col = cg * 192 + (w * 3 + i) * 16 + lr;
        bcol[i] = b1s[col];
#pragma unroll
        for (int kk = 0; kk < 6; ++kk)
            bW[i][kk] = *(const bf16x8*)(w1t + (col * 192 + kk * 32 + lg * 8));
    }

    __bf16* qk_dst = (cg == 0) ? qf : kf;
    __bf16* stg = Stg[w];

    // A staging: 16 rows x 192 cols fp32 = 768 f32x4 chunks, 3 per thread
    const int c0 = tid;
    auto stage = [&](int t, int buf) {
        const float* src = x + ((size_t)b * SEQ + t * 16) * DIM;
#pragma unroll
        for (int j = 0; j < 3; ++j) {
            int c = c0 + j * 256;
            int row = c / 48, c4 = (c % 48) * 4;
            f32x4 v = *(const f32x4*)&src[row * DIM + c4];
            bf16x4 pk;
            pk[0] = (__bf16)v[0]; pk[1] = (__bf16)v[1];
            pk[2] = (__bf16)v[2]; pk[3] = (__bf16)v[3];
            *(bf16x4*)&As[buf][row * 200 + c4] = pk;
        }
    };

    stage(0, 0);

    for (int t = 0; t < 9; ++t) {
        // prefetch next tile into regs
        f32x4 nxt[3];
        if (t < 8) {
            const float* src = x + ((size_t)b * SEQ + (t + 1) * 16) * DIM;
#pragma unroll
            for (int j = 0; j < 3; ++j) {
                int c = c0 + j * 256;
                int row = c / 48, c4 = (c % 48) * 4;
                nxt[j] = *(const f32x4*)&src[row * DIM + c4];
            }
        }
        lds_barrier();
        const __bf16* A = As[t & 1];
        f32x4 acc[3];
#pragma unroll
        for (int i = 0; i < 3; ++i) acc[i] = zf;
#pragma unroll
        for (int kk = 0; kk < 6; ++kk) {
            bf16x8 aF = *(const bf16x8*)&A[lr * 200 + kk * 32 + lg * 8];
#pragma unroll
            for (int i = 0; i < 3; ++i)
                acc[i] = __builtin_amdgcn_mfma_f32_16x16x32_bf16(aF, bW[i][kk], acc[i], 0, 0, 0);
        }

        // ---- epilogue
        if (cg < 2) {
            // restage to wave-private LDS [16 m][56] (+bias, bf16)
#pragma unroll
            for (int i = 0; i < 3; ++i)
#pragma unroll
                for (int r = 0; r < 4; ++r)
                    stg[(lg * 4 + r) * 56 + i * 16 + lr] = (__bf16)(acc[i][r] + bcol[i]);
            // wave-internal readback (compiler orders via lgkmcnt) + 16B stores
            // chunk c in [0,96): m=c/6, c8=c%6 ; dst j2 = w*48 + c8*8
#pragma unroll
            for (int rep = 0; rep < 2; ++rep) {
                int c = lane + rep * 64;
                if (rep == 0 || lane < 32) {
                    int m = c / 6, c8 = c % 6;
                    bf16x8 v = *(bf16x8*)&stg[m * 56 + c8 * 8];
                    int j2 = w * 48 + c8 * 8;
                    int h = j2 >> 5, j = j2 & 31;
                    size_t bh = (size_t)b * NH + h;
                    *(bf16x8*)&qk_dst[bh * BH_STRIDE + (size_t)(t * 16 + m) * HD + j] = v;
                }
            }
        } else {
            const int m = t * 16 + lg * 4;
#pragma unroll
            for (int i = 0; i < 3; ++i) {
                int j2 = (w * 3 + i) * 16 + lr;
                int h = j2 >> 5, j = j2 & 31;
                size_t bh = (size_t)b * NH + h;
                bf16x4 pk;
#pragma unroll
                for (int r = 0; r < 4; ++r) pk[r] = (__bf16)(acc[i][r] + bcol[i]);
                *(bf16x4*)&vtf[bh * BH_STRIDE + (size_t)j * SEQ + m] = pk;
            }
        }

        if (t < 8) {
#pragma unroll
            for (int j = 0; j < 3; ++j) {
                int c = c0 + j * 256;
                int row = c / 48, c4 = (c % 48) * 4;
                f32x4 v = nxt[j];
                bf16x4 pk;
                pk[0] = (__bf16)v[0]; pk[1] = (__bf16)v[1];
                pk[2] = (__bf16)v[2]; pk[3] = (__bf16)v[3];
                *(bf16x4*)&As[(t + 1) & 1][row * 200 + c4] = pk;
            }
        }
    }
}

// ---------------------------------------------------------------------------
// Attention-only per (b,h) (R12-proven): K,V cooperatively staged, Q per-lane
// direct, bias L2, ONE barrier, R9 P2/softmax/P3. LDS 32768 B.
// ---------------------------------------------------------------------------
__global__ __launch_bounds__(576, 2) void k_attn3(char* __restrict__ ws) {
    const __bf16* bmB = (const __bf16*)(ws + WS_BM);
    const __bf16* qf  = (const __bf16*)(ws + WS_QF);
    const __bf16* kf  = (const __bf16*)(ws + WS_KF);
    const __bf16* vtf = (const __bf16*)(ws + WS_VT);
    __bf16* opre = (__bf16*)(ws + WS_QF);   // alias: own slice, read-then-write

    __shared__ char smem[32768];
    __bf16* Ks  = (__bf16*)smem;             // [144][40]  11520 B
    __bf16* Vt  = (__bf16*)(smem + 11520);   // [32][152]   9728 B
    __bf16* Pws = (__bf16*)(smem + 21248);   // 9 x [16][40] wave-private

    const int bx = blockIdx.x;               // 6144 = 6 h-groups x 1024 b
    const int h  = bx >> 10;
    const int b  = bx & 1023;
    const size_t bh = (size_t)(b * NH + h);

    const int tid  = threadIdx.x;
    const int w    = tid >> 6;
    const int lane = tid & 63;
    const int lr   = lane & 15;
    const int lg   = lane >> 4;
    const int m0   = w * 16;
    const f32x4 zf = {0.f, 0.f, 0.f, 0.f};
    const bf16x8 zb = {(__bf16)0.f,(__bf16)0.f,(__bf16)0.f,(__bf16)0.f,
                       (__bf16)0.f,(__bf16)0.f,(__bf16)0.f,(__bf16)0.f};

    // ---- issue all global loads up front
    bf16x8 kch = *(const bf16x8*)(kf  + bh * BH_STRIDE + (size_t)tid * 8);
    bf16x8 vch = *(const bf16x8*)(vtf + bh * BH_STRIDE + (size_t)tid * 8);
    bf16x8 qF  = *(const bf16x8*)(qf  + bh * BH_STRIDE + (size_t)(m0 + lr) * HD + lg * 8);
    bf16x4 bb[9];
    {
        const __bf16* bmh = bmB + h * 20736 + (m0 + lr) * SEQ;
#pragma unroll
        for (int i = 0; i < 9; ++i) bb[i] = *(const bf16x4*)&bmh[i * 16 + lg * 4];
    }

    // ---- stage to LDS
    *(bf16x8*)&Ks[(tid >> 2) * 40 + (tid & 3) * 8] = kch;
    {
        int vr = tid / 18, vc = tid % 18;
        *(bf16x8*)&Vt[vr * 152 + vc * 8] = vch;
    }
    lds_barrier();   // the ONE barrier

    // ---- P2: S^T = mfma(K,Q); +bias; in-register softmax
    f32x4 st[9];
#pragma unroll
    for (int i = 0; i < 9; ++i) {
        bf16x8 aF = *(bf16x8*)&Ks[(i * 16 + lr) * 40 + lg * 8];
        st[i] = __builtin_amdgcn_mfma_f32_16x16x32_bf16(aF, qF, zf, 0, 0, 0);
    }
    float mx = -3.0e38f;
#pragma unroll
    for (int i = 0; i < 9; ++i)
#pragma unroll
        for (int r = 0; r < 4; ++r) {
            st[i][r] += (float)bb[i][r];
            mx = fmaxf(mx, st[i][r]);
        }
    mx = fmaxf(mx, __shfl_xor(mx, 16));
    mx = fmaxf(mx, __shfl_xor(mx, 32));
    float sum = 0.f;
#pragma unroll
    for (int i = 0; i < 9; ++i)
#pragma unroll
        for (int r = 0; r < 4; ++r) {
            float e = __expf(st[i][r] - mx);
            st[i][r] = e;
            sum += e;
        }
    sum += __shfl_xor(sum, 16);
    sum += __shfl_xor(sum, 32);
    float inv = 1.f / sum;
#pragma unroll
    for (int i = 0; i < 9; ++i)
#pragma unroll
        for (int r = 0; r < 4; ++r) st[i][r] *= inv;

    // ---- P3: O = P @ V via per-wave P scratch
    __bf16* Pw = Pws + w * 640;    // [16][40]
    f32x4 o0 = zf, o1 = zf;
#pragma unroll
    for (int s = 0; s < 4; ++s) {
#pragma unroll
        for (int d = 0; d < 2; ++d) {
            int ii = 2 * s + d;
            bf16x4 pk;
#pragma unroll
            for (int r = 0; r < 4; ++r) pk[r] = (__bf16)st[ii][r];
            *(bf16x4*)&Pw[lr * 40 + d * 16 + lg * 4] = pk;
        }
        bf16x8 aP  = *(bf16x8*)&Pw[lr * 40 + lg * 8];
        bf16x8 v0F = *(bf16x8*)&Vt[lr * 152 + s * 32 + lg * 8];
        bf16x8 v1F = *(bf16x8*)&Vt[(16 + lr) * 152 + s * 32 + lg * 8];
        o0 = __builtin_amdgcn_mfma_f32_16x16x32_bf16(aP, v0F, o0, 0, 0, 0);
        o1 = __builtin_amdgcn_mfma_f32_16x16x32_bf16(aP, v1F, o1, 0, 0, 0);
    }
    {   // tail keys 128..143: lanes lg>=2 supply zeros
        bf16x4 pk;
#pragma unroll
        for (int r = 0; r < 4; ++r) pk[r] = (__bf16)st[8][r];
        *(bf16x4*)&Pw[lr * 40 + lg * 4] = pk;
        bf16x8 aP = zb, v0F = zb, v1F = zb;
        if (lg < 2) {
            aP  = *(bf16x8*)&Pw[lr * 40 + lg * 8];
            v0F = *(bf16x8*)&Vt[lr * 152 + 128 + lg * 8];
            v1F = *(bf16x8*)&Vt[(16 + lr) * 152 + 128 + lg * 8];
        }
        o0 = __builtin_amdgcn_mfma_f32_16x16x32_bf16(aP, v0F, o0, 0, 0, 0);
        o1 = __builtin_amdgcn_mfma_f32_16x16x32_bf16(aP, v1F, o1, 0, 0, 0);
    }

    // ---- O restage (coalesce) + store to opre (h-major, aliases own q slice)
#pragma unroll
    for (int r = 0; r < 4; ++r) {
        Pw[(lg * 4 + r) * 40 + lr]      = (__bf16)o0[r];
        Pw[(lg * 4 + r) * 40 + 16 + lr] = (__bf16)o1[r];
    }
    {
        int row = lane >> 2, c = lane & 3;
        bf16x8 ov = *(bf16x8*)&Pw[row * 40 + c * 8];
        *(bf16x8*)&opre[bh * BH_STRIDE + (size_t)(m0 + row) * HD + c * 8] = ov;
    }
}

// ---------------------------------------------------------------------------
// Out-projection (R12-proven): register-B, h-major gather, dbuf staging.
// ---------------------------------------------------------------------------
__global__ __launch_bounds__(256, 3) void k_proj(
        const char* __restrict__ ws, const float* __restrict__ b2,
        float* __restrict__ out) {
    const __bf16* opre = (const __bf16*)(ws + WS_QF);
    const __bf16* w2t  = (const __bf16*)(ws + WS_W2T);
    __shared__ __bf16 As[2][16 * 200];

    const int tid = threadIdx.x;
    const int w = tid >> 6, lr = tid & 15, lg = (tid & 63) >> 4;
    const int b = blockIdx.x;
    const f32x4 zf = {0.f, 0.f, 0.f, 0.f};

    bf16x8 bW[3][6];
    float bcol[3];
#pragma unroll
    for (int i = 0; i < 3; ++i) {
        int col = (w * 3 + i) * 16 + lr;
        bcol[i] = b2[col];
#pragma unroll
        for (int kk = 0; kk < 6; ++kk)
            bW[i][kk] = *(const bf16x8*)(w2t + (col * 192 + kk * 32 + lg * 8));
    }

    auto src_of = [&](int t, int c) -> const __bf16* {
        int lrow = c / 24, c8 = c % 24;
        int h = c8 >> 2, col32 = (c8 & 3) * 8;
        return opre + ((size_t)(b * NH + h)) * BH_STRIDE
                    + (size_t)(t * 16 + lrow) * HD + col32;
    };
    auto dst_of = [&](int buf, int c) -> __bf16* {
        int lrow = c / 24, c8 = c % 24;
        return &As[buf][lrow * 200 + c8 * 8];
    };

    {
        *(bf16x8*)dst_of(0, tid) = *(const bf16x8*)src_of(0, tid);
        if (tid < 128)
            *(bf16x8*)dst_of(0, tid + 256) = *(const bf16x8*)src_of(0, tid + 256);
    }

    for (int t = 0; t < 9; ++t) {
        bf16x8 n0, n1;
        if (t < 8) {
            n0 = *(const bf16x8*)src_of(t + 1, tid);
            if (tid < 128) n1 = *(const bf16x8*)src_of(t + 1, tid + 256);
        }
        lds_barrier();
        const __bf16* A = As[t & 1];
        f32x4 acc[3];
#pragma unroll
        for (int i = 0; i < 3; ++i) acc[i] = zf;
#pragma unroll
        for (int kk = 0; kk < 6; ++kk) {
            bf16x8 aF = *(const bf16x8*)&A[lr * 200 + kk * 32 + lg * 8];
#pragma unroll
            for (int i = 0; i < 3; ++i)
                acc[i] = __builtin_amdgcn_mfma_f32_16x16x32_bf16(aF, bW[i][kk], acc[i], 0, 0, 0);
        }
        size_t row0 = (size_t)b * SEQ + t * 16;
#pragma unroll
        for (int i = 0; i < 3; ++i) {
            int col = (w * 3 + i) * 16 + lr;
#pragma unroll
            for (int r = 0; r < 4; ++r)
                out[(row0 + lg * 4 + r) * DIM + col] = acc[i][r] + bcol[i];
        }
        if (t < 8) {
            *(bf16x8*)dst_of((t + 1) & 1, tid) = n0;
            if (tid < 128) *(bf16x8*)dst_of((t + 1) & 1, tid + 256) = n1;
        }
    }
}

// ---------------------------------------------------------------------------
extern "C" void kernel_launch(void* const* d_in, const int* in_sizes, int n_in,
                              void* d_out, int out_size, void* d_ws, size_t ws_size,
                              hipStream_t stream) {
    const float* x    = (const float*)d_in[0];
    const float* w1   = (const float*)d_in[1];
    const float* b1   = (const float*)d_in[2];
    const float* w2   = (const float*)d_in[3];
    const float* b2   = (const float*)d_in[4];
    const float* bt   = (const float*)d_in[5];
    const int*   pidx = (const int*)d_in[6];
    const int*   mask = (const int*)d_in[7];
    float* out = (float*)d_out;
    char*  ws  = (char*)d_ws;

    k_prep<<<658, 256, 0, stream>>>(w1, w2, b1, bt, pidx, mask, ws);
    k_qkv<<<3072, 256, 0, stream>>>(x, ws);
    k_attn3<<<BATCH * NH, 576, 0, stream>>>(ws);
    k_proj<<<BATCH, 256, 0, stream>>>(ws, b2, out);
}

// Round 19
// 185.112 us; speedup vs baseline: 2.1903x; 1.0342x over previous
//
#include <hip/hip_runtime.h>

#define BATCH 1024
#define SEQ   144
#define DIM   192
#define NH    6
#define HD    32
#define SCALE 0.17677669529663687f   // 1/sqrt(32)

typedef __bf16 bf16x8 __attribute__((ext_vector_type(8)));
typedef __bf16 bf16x4 __attribute__((ext_vector_type(4)));
typedef float  f32x4  __attribute__((ext_vector_type(4)));

// LDS-only barrier (proven R9): orders ds_write->ds_read without draining vmcnt.
__device__ __forceinline__ void lds_barrier() {
    __builtin_amdgcn_sched_barrier(0);
    asm volatile("s_waitcnt lgkmcnt(0)" ::: "memory");
    __builtin_amdgcn_s_barrier();
    __builtin_amdgcn_sched_barrier(0);
}

// ---- workspace layout (bytes) ----
#define WS_W1T   0          // bf16 [576][192]  w1t[c][k] = w1[k][c] (*SCALE for c<192)
#define WS_W2T   221184     // bf16 [192][192]  w2t[n][k] = w2[k][n]
#define WS_B1S   294912     // f32  [576]       b1 (*SCALE for c<192)
#define WS_BM    297216     // bf16 [6][144][144]  bm[h][query][key] = bias + mask
#define WS_QF    546048     // bf16 [1024*6][144][32]  q ; aliased as opre after read
#define WS_KF    57169152   // bf16 [1024*6][144][32]  k
#define WS_VT    113792256  // bf16 [1024*6][32][144]  v^T
// total need 170415360 B (confirmed available in round 6)

#define BH_STRIDE 4608      // 144*32 elems per (b,h)

// ---------------------------------------------------------------------------
__global__ __launch_bounds__(256) void k_prep(
        const float* __restrict__ w1, const float* __restrict__ w2,
        const float* __restrict__ b1, const float* __restrict__ bt,
        const int* __restrict__ pidx, const int* __restrict__ mask,
        char* __restrict__ ws) {
    __bf16* w1t = (__bf16*)(ws + WS_W1T);
    __bf16* w2t = (__bf16*)(ws + WS_W2T);
    float*  b1s = (float*)(ws + WS_B1S);
    __bf16* bm  = (__bf16*)(ws + WS_BM);
    const int blk = blockIdx.x, t = threadIdx.x;
    if (blk < 432) {
        int idx = blk * 256 + t;
        int k = idx / 576, c = idx % 576;
        float v = w1[idx] * (c < 192 ? SCALE : 1.0f);
        w1t[c * 192 + k] = (__bf16)v;
    } else if (blk < 576) {
        int idx = (blk - 432) * 256 + t;
        int k = idx / 192, n = idx % 192;
        w2t[n * 192 + k] = (__bf16)w2[idx];
    } else if (blk < 657) {
        int idx = (blk - 576) * 256 + t;   // idx = query*144 + key
        int p = pidx[idx];
        float add = (mask[idx] == 0) ? -1e9f : 0.0f;
#pragma unroll
        for (int h = 0; h < NH; ++h)
            bm[h * 20736 + idx] = (__bf16)(bt[p * NH + h] + add);
    } else {
        for (int c = t; c < 576; c += 256)
            b1s[c] = b1[c] * (c < 192 ? SCALE : 1.0f);
    }
}

// ---------------------------------------------------------------------------
// QKV GEMM, TRIO-MERGED (R15 body, FIXED launch bounds): one 768-thread block
// (12 waves) per b computes all 576 output cols. Wave w: group cg=w/4
// (0=q,1=k,2=v), 48-col slice (w%4)*48. X staged ONCE per tile for all
// groups. __launch_bounds__(768) -> implied VGPR cap 170, natural ~80 regs,
// 2 blocks/CU co-resident (24 waves/CU). LDS 27136 B.
// (R15's regression was __launch_bounds__(768,6) squeezing VGPR to 40.)
// ---------------------------------------------------------------------------
__global__ __launch_bounds__(768) void k_qkv(
        const float* __restrict__ x, char* __restrict__ ws) {
    const __bf16* w1t = (const __bf16*)(ws + WS_W1T);
    const float*  b1s = (const float*)(ws + WS_B1S);
    __bf16* qf  = (__bf16*)(ws + WS_QF);
    __bf16* kf  = (__bf16*)(ws + WS_KF);
    __bf16* vtf = (__bf16*)(ws + WS_VT);

    __shared__ __bf16 As[2][16 * 200];      // 12800 B
    __shared__ __bf16 Stg[8][16 * 56];      // 14336 B: q/k waves' restage

    const int tid  = threadIdx.x;
    const int w    = tid >> 6;              // 0..11
    const int lane = tid & 63;
    const int lr   = lane & 15;
    const int lg   = lane >> 4;
    const int cg   = w >> 2;                // 0=q, 1=k, 2=v
    const int wp   = w & 3;                 // wave-in-group: 48-col slice
    const int b    = blockIdx.x;
    const f32x4 zf = {0.f, 0.f, 0.f, 0.f};

    // persistent B-frags + bias for this wave's 48 cols
    bf16x8 bW[3][6];
    float bcol[3];
#pragma unroll
    for (int i = 0; i < 3; ++i) {
        int col = cg * 192 + (wp * 3 + i) * 16 + lr;
        bcol[i] = b1s[col];
#pragma unroll
        for (int kk = 0; kk < 6; ++kk)
            bW[i][kk] = *(const bf16x8*)(w1t + (col * 192 + kk * 32 + lg * 8));
    }

    __bf16* qk_dst = (cg == 0) ? qf : kf;
    __bf16* stg = (cg < 2) ? Stg[w] : nullptr;

    // A staging: 16 rows x 192 cols fp32 = 768 f32x4 chunks, 1 per thread
    auto stage = [&](int t, int buf) {
        const float* src = x + ((size_t)b * SEQ + t * 16) * DIM;
        int row = tid / 48, c4 = (tid % 48) * 4;
        f32x4 v = *(const f32x4*)&src[row * DIM + c4];
        bf16x4 pk;
        pk[0] = (__bf16)v[0]; pk[1] = (__bf16)v[1];
        pk[2] = (__bf16)v[2]; pk[3] = (__bf16)v[3];
        *(bf16x4*)&As[buf][row * 200 + c4] = pk;
    };

    stage(0, 0);

    for (int t = 0; t < 9; ++t) {
        // prefetch next tile into regs
        f32x4 nxt;
        if (t < 8) {
            const float* src = x + ((size_t)b * SEQ + (t + 1) * 16) * DIM;
            int row = tid / 48, c4 = (tid % 48) * 4;
            nxt = *(const f32x4*)&src[row * DIM + c4];
        }
        lds_barrier();
        const __bf16* A = As[t & 1];
        f32x4 acc[3];
#pragma unroll
        for (int i = 0; i < 3; ++i) acc[i] = zf;
#pragma unroll
        for (int kk = 0; kk < 6; ++kk) {
            bf16x8 aF = *(const bf16x8*)&A[lr * 200 + kk * 32 + lg * 8];
#pragma unroll
            for (int i = 0; i < 3; ++i)
                acc[i] = __builtin_amdgcn_mfma_f32_16x16x32_bf16(aF, bW[i][kk], acc[i], 0, 0, 0);
        }

        // ---- epilogue
        if (cg < 2) {
            // restage to wave-private LDS [16 m][56] (+bias, bf16)
#pragma unroll
            for (int i = 0; i < 3; ++i)
#pragma unroll
                for (int r = 0; r < 4; ++r)
                    stg[(lg * 4 + r) * 56 + i * 16 + lr] = (__bf16)(acc[i][r] + bcol[i]);
            // wave-internal readback (compiler orders via lgkmcnt) + 16B stores
            // chunk c in [0,96): m=c/6, c8=c%6 ; dst j2 = wp*48 + c8*8
#pragma unroll
            for (int rep = 0; rep < 2; ++rep) {
                int c = lane + rep * 64;
                if (rep == 0 || lane < 32) {
                    int m = c / 6, c8 = c % 6;
                    bf16x8 v = *(bf16x8*)&stg[m * 56 + c8 * 8];
                    int j2 = wp * 48 + c8 * 8;
                    int h = j2 >> 5, j = j2 & 31;
                    size_t bh = (size_t)b * NH + h;
                    *(bf16x8*)&qk_dst[bh * BH_STRIDE + (size_t)(t * 16 + m) * HD + j] = v;
                }
            }
        } else {
            const int m = t * 16 + lg * 4;
#pragma unroll
            for (int i = 0; i < 3; ++i) {
                int j2 = (wp * 3 + i) * 16 + lr;
                int h = j2 >> 5, j = j2 & 31;
                size_t bh = (size_t)b * NH + h;
                bf16x4 pk;
#pragma unroll
                for (int r = 0; r < 4; ++r) pk[r] = (__bf16)(acc[i][r] + bcol[i]);
                *(bf16x4*)&vtf[bh * BH_STRIDE + (size_t)j * SEQ + m] = pk;
            }
        }

        if (t < 8) {
            int row = tid / 48, c4 = (tid % 48) * 4;
            f32x4 v = nxt;
            bf16x4 pk;
            pk[0] = (__bf16)v[0]; pk[1] = (__bf16)v[1];
            pk[2] = (__bf16)v[2]; pk[3] = (__bf16)v[3];
            *(bf16x4*)&As[(t + 1) & 1][row * 200 + c4] = pk;
        }
    }
}

// ---------------------------------------------------------------------------
// Attention-only per (b,h) (R12-proven): K,V cooperatively staged, Q per-lane
// direct, bias L2, ONE barrier, R9 P2/softmax/P3. LDS 32768 B.
// ---------------------------------------------------------------------------
__global__ __launch_bounds__(576, 2) void k_attn3(char* __restrict__ ws) {
    const __bf16* bmB = (const __bf16*)(ws + WS_BM);
    const __bf16* qf  = (const __bf16*)(ws + WS_QF);
    const __bf16* kf  = (const __bf16*)(ws + WS_KF);
    const __bf16* vtf = (const __bf16*)(ws + WS_VT);
    __bf16* opre = (__bf16*)(ws + WS_QF);   // alias: own slice, read-then-write

    __shared__ char smem[32768];
    __bf16* Ks  = (__bf16*)smem;             // [144][40]  11520 B
    __bf16* Vt  = (__bf16*)(smem + 11520);   // [32][152]   9728 B
    __bf16* Pws = (__bf16*)(smem + 21248);   // 9 x [16][40] wave-private

    const int bx = blockIdx.x;               // 6144 = 6 h-groups x 1024 b
    const int h  = bx >> 10;
    const int b  = bx & 1023;
    const size_t bh = (size_t)(b * NH + h);

    const int tid  = threadIdx.x;
    const int w    = tid >> 6;
    const int lane = tid & 63;
    const int lr   = lane & 15;
    const int lg   = lane >> 4;
    const int m0   = w * 16;
    const f32x4 zf = {0.f, 0.f, 0.f, 0.f};
    const bf16x8 zb = {(__bf16)0.f,(__bf16)0.f,(__bf16)0.f,(__bf16)0.f,
                       (__bf16)0.f,(__bf16)0.f,(__bf16)0.f,(__bf16)0.f};

    // ---- issue all global loads up front
    bf16x8 kch = *(const bf16x8*)(kf  + bh * BH_STRIDE + (size_t)tid * 8);
    bf16x8 vch = *(const bf16x8*)(vtf + bh * BH_STRIDE + (size_t)tid * 8);
    bf16x8 qF  = *(const bf16x8*)(qf  + bh * BH_STRIDE + (size_t)(m0 + lr) * HD + lg * 8);
    bf16x4 bb[9];
    {
        const __bf16* bmh = bmB + h * 20736 + (m0 + lr) * SEQ;
#pragma unroll
        for (int i = 0; i < 9; ++i) bb[i] = *(const bf16x4*)&bmh[i * 16 + lg * 4];
    }

    // ---- stage to LDS
    *(bf16x8*)&Ks[(tid >> 2) * 40 + (tid & 3) * 8] = kch;
    {
        int vr = tid / 18, vc = tid % 18;
        *(bf16x8*)&Vt[vr * 152 + vc * 8] = vch;
    }
    lds_barrier();   // the ONE barrier

    // ---- P2: S^T = mfma(K,Q); +bias; in-register softmax
    f32x4 st[9];
#pragma unroll
    for (int i = 0; i < 9; ++i) {
        bf16x8 aF = *(bf16x8*)&Ks[(i * 16 + lr) * 40 + lg * 8];
        st[i] = __builtin_amdgcn_mfma_f32_16x16x32_bf16(aF, qF, zf, 0, 0, 0);
    }
    float mx = -3.0e38f;
#pragma unroll
    for (int i = 0; i < 9; ++i)
#pragma unroll
        for (int r = 0; r < 4; ++r) {
            st[i][r] += (float)bb[i][r];
            mx = fmaxf(mx, st[i][r]);
        }
    mx = fmaxf(mx, __shfl_xor(mx, 16));
    mx = fmaxf(mx, __shfl_xor(mx, 32));
    float sum = 0.f;
#pragma unroll
    for (int i = 0; i < 9; ++i)
#pragma unroll
        for (int r = 0; r < 4; ++r) {
            float e = __expf(st[i][r] - mx);
            st[i][r] = e;
            sum += e;
        }
    sum += __shfl_xor(sum, 16);
    sum += __shfl_xor(sum, 32);
    float inv = 1.f / sum;
#pragma unroll
    for (int i = 0; i < 9; ++i)
#pragma unroll
        for (int r = 0; r < 4; ++r) st[i][r] *= inv;

    // ---- P3: O = P @ V via per-wave P scratch
    __bf16* Pw = Pws + w * 640;    // [16][40]
    f32x4 o0 = zf, o1 = zf;
#pragma unroll
    for (int s = 0; s < 4; ++s) {
#pragma unroll
        for (int d = 0; d < 2; ++d) {
            int ii = 2 * s + d;
            bf16x4 pk;
#pragma unroll
            for (int r = 0; r < 4; ++r) pk[r] = (__bf16)st[ii][r];
            *(bf16x4*)&Pw[lr * 40 + d * 16 + lg * 4] = pk;
        }
        bf16x8 aP  = *(bf16x8*)&Pw[lr * 40 + lg * 8];
        bf16x8 v0F = *(bf16x8*)&Vt[lr * 152 + s * 32 + lg * 8];
        bf16x8 v1F = *(bf16x8*)&Vt[(16 + lr) * 152 + s * 32 + lg * 8];
        o0 = __builtin_amdgcn_mfma_f32_16x16x32_bf16(aP, v0F, o0, 0, 0, 0);
        o1 = __builtin_amdgcn_mfma_f32_16x16x32_bf16(aP, v1F, o1, 0, 0, 0);
    }
    {   // tail keys 128..143: lanes lg>=2 supply zeros
        bf16x4 pk;
#pragma unroll
        for (int r = 0; r < 4; ++r) pk[r] = (__bf16)st[8][r];
        *(bf16x4*)&Pw[lr * 40 + lg * 4] = pk;
        bf16x8 aP = zb, v0F = zb, v1F = zb;
        if (lg < 2) {
            aP  = *(bf16x8*)&Pw[lr * 40 + lg * 8];
            v0F = *(bf16x8*)&Vt[lr * 152 + 128 + lg * 8];
            v1F = *(bf16x8*)&Vt[(16 + lr) * 152 + 128 + lg * 8];
        }
        o0 = __builtin_amdgcn_mfma_f32_16x16x32_bf16(aP, v0F, o0, 0, 0, 0);
        o1 = __builtin_amdgcn_mfma_f32_16x16x32_bf16(aP, v1F, o1, 0, 0, 0);
    }

    // ---- O restage (coalesce) + store to opre (h-major, aliases own q slice)
#pragma unroll
    for (int r = 0; r < 4; ++r) {
        Pw[(lg * 4 + r) * 40 + lr]      = (__bf16)o0[r];
        Pw[(lg * 4 + r) * 40 + 16 + lr] = (__bf16)o1[r];
    }
    {
        int row = lane >> 2, c = lane & 3;
        bf16x8 ov = *(bf16x8*)&Pw[row * 40 + c * 8];
        *(bf16x8*)&opre[bh * BH_STRIDE + (size_t)(m0 + row) * HD + c * 8] = ov;
    }
}

// ---------------------------------------------------------------------------
// Out-projection (R12-proven): register-B, h-major gather, dbuf staging.
// ---------------------------------------------------------------------------
__global__ __launch_bounds__(256, 3) void k_proj(
        const char* __restrict__ ws, const float* __restrict__ b2,
        float* __restrict__ out) {
    const __bf16* opre = (const __bf16*)(ws + WS_QF);
    const __bf16* w2t  = (const __bf16*)(ws + WS_W2T);
    __shared__ __bf16 As[2][16 * 200];

    const int tid = threadIdx.x;
    const int w = tid >> 6, lr = tid & 15, lg = (tid & 63) >> 4;
    const int b = blockIdx.x;
    const f32x4 zf = {0.f, 0.f, 0.f, 0.f};

    bf16x8 bW[3][6];
    float bcol[3];
#pragma unroll
    for (int i = 0; i < 3; ++i) {
        int col = (w * 3 + i) * 16 + lr;
        bcol[i] = b2[col];
#pragma unroll
        for (int kk = 0; kk < 6; ++kk)
            bW[i][kk] = *(const bf16x8*)(w2t + (col * 192 + kk * 32 + lg * 8));
    }

    auto src_of = [&](int t, int c) -> const __bf16* {
        int lrow = c / 24, c8 = c % 24;
        int h = c8 >> 2, col32 = (c8 & 3) * 8;
        return opre + ((size_t)(b * NH + h)) * BH_STRIDE
                    + (size_t)(t * 16 + lrow) * HD + col32;
    };
    auto dst_of = [&](int buf, int c) -> __bf16* {
        int lrow = c / 24, c8 = c % 24;
        return &As[buf][lrow * 200 + c8 * 8];
    };

    {
        *(bf16x8*)dst_of(0, tid) = *(const bf16x8*)src_of(0, tid);
        if (tid < 128)
            *(bf16x8*)dst_of(0, tid + 256) = *(const bf16x8*)src_of(0, tid + 256);
    }

    for (int t = 0; t < 9; ++t) {
        bf16x8 n0, n1;
        if (t < 8) {
            n0 = *(const bf16x8*)src_of(t + 1, tid);
            if (tid < 128) n1 = *(const bf16x8*)src_of(t + 1, tid + 256);
        }
        lds_barrier();
        const __bf16* A = As[t & 1];
        f32x4 acc[3];
#pragma unroll
        for (int i = 0; i < 3; ++i) acc[i] = zf;
#pragma unroll
        for (int kk = 0; kk < 6; ++kk) {
            bf16x8 aF = *(const bf16x8*)&A[lr * 200 + kk * 32 + lg * 8];
#pragma unroll
            for (int i = 0; i < 3; ++i)
                acc[i] = __builtin_amdgcn_mfma_f32_16x16x32_bf16(aF, bW[i][kk], acc[i], 0, 0, 0);
        }
        size_t row0 = (size_t)b * SEQ + t * 16;
#pragma unroll
        for (int i = 0; i < 3; ++i) {
            int col = (w * 3 + i) * 16 + lr;
#pragma unroll
            for (int r = 0; r < 4; ++r)
                out[(row0 + lg * 4 + r) * DIM + col] = acc[i][r] + bcol[i];
        }
        if (t < 8) {
            *(bf16x8*)dst_of((t + 1) & 1, tid) = n0;
            if (tid < 128) *(bf16x8*)dst_of((t + 1) & 1, tid + 256) = n1;
        }
    }
}

// ---------------------------------------------------------------------------
extern "C" void kernel_launch(void* const* d_in, const int* in_sizes, int n_in,
                              void* d_out, int out_size, void* d_ws, size_t ws_size,
                              hipStream_t stream) {
    const float* x    = (const float*)d_in[0];
    const float* w1   = (const float*)d_in[1];
    const float* b1   = (const float*)d_in[2];
    const float* w2   = (const float*)d_in[3];
    const float* b2   = (const float*)d_in[4];
    const float* bt   = (const float*)d_in[5];
    const int*   pidx = (const int*)d_in[6];
    const int*   mask = (const int*)d_in[7];
    float* out = (float*)d_out;
    char*  ws  = (char*)d_ws;

    k_prep<<<658, 256, 0, stream>>>(w1, w2, b1, bt, pidx, mask, ws);
    k_qkv<<<BATCH, 768, 0, stream>>>(x, ws);
    k_attn3<<<BATCH * NH, 576, 0, stream>>>(ws);
    k_proj<<<BATCH, 256, 0, stream>>>(ws, b2, out);
}

// Round 20
// 173.815 us; speedup vs baseline: 2.3327x; 1.0650x over previous
//
#include <hip/hip_runtime.h>

#define BATCH 1024
#define SEQ   144
#define DIM   192
#define NH    6
#define HD    32
#define SCALE 0.17677669529663687f   // 1/sqrt(32)

typedef __bf16 bf16x8 __attribute__((ext_vector_type(8)));
typedef __bf16 bf16x4 __attribute__((ext_vector_type(4)));
typedef float  f32x4  __attribute__((ext_vector_type(4)));

// LDS-only barrier (proven R9): orders ds_write->ds_read without draining vmcnt.
__device__ __forceinline__ void lds_barrier() {
    __builtin_amdgcn_sched_barrier(0);
    asm volatile("s_waitcnt lgkmcnt(0)" ::: "memory");
    __builtin_amdgcn_s_barrier();
    __builtin_amdgcn_sched_barrier(0);
}

// ---- workspace layout (bytes) ----
#define WS_W1T   0          // bf16 [576][192]  w1t[c][k] = w1[k][c] (*SCALE for c<192)
#define WS_W2T   221184     // bf16 [192][192]  w2t[n][k] = w2[k][n]
#define WS_B1S   294912     // f32  [576]       b1 (*SCALE for c<192)
#define WS_BM    297216     // bf16 [6][144][144]  bm[h][query][key] = bias + mask
#define WS_QF    546048     // bf16 [1024*6][144][32]  q ; aliased as opre after read
#define WS_KF    57169152   // bf16 [1024*6][144][32]  k
#define WS_VT    113792256  // bf16 [1024*6][32][144]  v^T
// total need 170415360 B (confirmed available in round 6)

#define BH_STRIDE 4608      // 144*32 elems per (b,h)

// ---------------------------------------------------------------------------
__global__ __launch_bounds__(256) void k_prep(
        const float* __restrict__ w1, const float* __restrict__ w2,
        const float* __restrict__ b1, const float* __restrict__ bt,
        const int* __restrict__ pidx, const int* __restrict__ mask,
        char* __restrict__ ws) {
    __bf16* w1t = (__bf16*)(ws + WS_W1T);
    __bf16* w2t = (__bf16*)(ws + WS_W2T);
    float*  b1s = (float*)(ws + WS_B1S);
    __bf16* bm  = (__bf16*)(ws + WS_BM);
    const int blk = blockIdx.x, t = threadIdx.x;
    if (blk < 432) {
        int idx = blk * 256 + t;
        int k = idx / 576, c = idx % 576;
        float v = w1[idx] * (c < 192 ? SCALE : 1.0f);
        w1t[c * 192 + k] = (__bf16)v;
    } else if (blk < 576) {
        int idx = (blk - 432) * 256 + t;
        int k = idx / 192, n = idx % 192;
        w2t[n * 192 + k] = (__bf16)w2[idx];
    } else if (blk < 657) {
        int idx = (blk - 576) * 256 + t;   // idx = query*144 + key
        int p = pidx[idx];
        float add = (mask[idx] == 0) ? -1e9f : 0.0f;
#pragma unroll
        for (int h = 0; h < NH; ++h)
            bm[h * 20736 + idx] = (__bf16)(bt[p * NH + h] + add);
    } else {
        for (int c = t; c < 576; c += 256)
            b1s[c] = b1[c] * (c < 192 ? SCALE : 1.0f);
    }
}

// ---------------------------------------------------------------------------
// QKV GEMM, TRIO-MERGED + 2-BATCH AMORTIZED: one 768-thread block handles
// TWO b's (grid 512). Wave w: group cg=w/4 (0=q,1=k,2=v), 48-col slice
// (w%4)*48; bW/bcol loaded ONCE per block (amortized over 18 tiles).
// Flattened 18-tile loop; dbuf staging pipelines seamlessly across the b
// boundary. LDS 27136 B; __launch_bounds__(768) (R19-proven, VGPR ~72).
// ---------------------------------------------------------------------------
__global__ __launch_bounds__(768) void k_qkv(
        const float* __restrict__ x, char* __restrict__ ws) {
    const __bf16* w1t = (const __bf16*)(ws + WS_W1T);
    const float*  b1s = (const float*)(ws + WS_B1S);
    __bf16* qf  = (__bf16*)(ws + WS_QF);
    __bf16* kf  = (__bf16*)(ws + WS_KF);
    __bf16* vtf = (__bf16*)(ws + WS_VT);

    __shared__ __bf16 As[2][16 * 200];      // 12800 B
    __shared__ __bf16 Stg[8][16 * 56];      // 14336 B: q/k waves' restage

    const int tid  = threadIdx.x;
    const int w    = tid >> 6;              // 0..11
    const int lane = tid & 63;
    const int lr   = lane & 15;
    const int lg   = lane >> 4;
    const int cg   = w >> 2;                // 0=q, 1=k, 2=v
    const int wp   = w & 3;                 // wave-in-group: 48-col slice
    const int b0   = blockIdx.x * 2;
    const f32x4 zf = {0.f, 0.f, 0.f, 0.f};

    // persistent B-frags + bias for this wave's 48 cols (loaded once / 2 b's)
    bf16x8 bW[3][6];
    float bcol[3];
#pragma unroll
    for (int i = 0; i < 3; ++i) {
        int col = cg * 192 + (wp * 3 + i) * 16 + lr;
        bcol[i] = b1s[col];
#pragma unroll
        for (int kk = 0; kk < 6; ++kk)
            bW[i][kk] = *(const bf16x8*)(w1t + (col * 192 + kk * 32 + lg * 8));
    }

    __bf16* qk_dst = (cg == 0) ? qf : kf;
    __bf16* stg = (cg < 2) ? Stg[w] : nullptr;

    const int srow = tid / 48, sc4 = (tid % 48) * 4;  // staging chunk coords

    // stage tile (b, t) into buf (1 f32x4 chunk per thread)
    auto stage_to = [&](int bb, int t, int buf) {
        const float* src = x + ((size_t)bb * SEQ + t * 16) * DIM;
        f32x4 v = *(const f32x4*)&src[srow * DIM + sc4];
        bf16x4 pk;
        pk[0] = (__bf16)v[0]; pk[1] = (__bf16)v[1];
        pk[2] = (__bf16)v[2]; pk[3] = (__bf16)v[3];
        *(bf16x4*)&As[buf][srow * 200 + sc4] = pk;
    };

    stage_to(b0, 0, 0);

    for (int u = 0; u < 18; ++u) {
        const int b = b0 + (u >= 9);
        const int t = (u >= 9) ? u - 9 : u;

        // prefetch next unit's tile into regs
        f32x4 nxt;
        if (u < 17) {
            const int nb = b0 + ((u + 1) >= 9);
            const int nt = ((u + 1) >= 9) ? u + 1 - 9 : u + 1;
            const float* src = x + ((size_t)nb * SEQ + nt * 16) * DIM;
            nxt = *(const f32x4*)&src[srow * DIM + sc4];
        }
        lds_barrier();
        const __bf16* A = As[u & 1];
        f32x4 acc[3];
#pragma unroll
        for (int i = 0; i < 3; ++i) acc[i] = zf;
#pragma unroll
        for (int kk = 0; kk < 6; ++kk) {
            bf16x8 aF = *(const bf16x8*)&A[lr * 200 + kk * 32 + lg * 8];
#pragma unroll
            for (int i = 0; i < 3; ++i)
                acc[i] = __builtin_amdgcn_mfma_f32_16x16x32_bf16(aF, bW[i][kk], acc[i], 0, 0, 0);
        }

        // ---- epilogue
        if (cg < 2) {
            // restage to wave-private LDS [16 m][56] (+bias, bf16)
#pragma unroll
            for (int i = 0; i < 3; ++i)
#pragma unroll
                for (int r = 0; r < 4; ++r)
                    stg[(lg * 4 + r) * 56 + i * 16 + lr] = (__bf16)(acc[i][r] + bcol[i]);
            // wave-internal readback (same-wave DS ordering) + 16B stores
            // chunk c in [0,96): m=c/6, c8=c%6 ; dst j2 = wp*48 + c8*8
#pragma unroll
            for (int rep = 0; rep < 2; ++rep) {
                int c = lane + rep * 64;
                if (rep == 0 || lane < 32) {
                    int m = c / 6, c8 = c % 6;
                    bf16x8 v = *(bf16x8*)&stg[m * 56 + c8 * 8];
                    int j2 = wp * 48 + c8 * 8;
                    int h = j2 >> 5, j = j2 & 31;
                    size_t bh = (size_t)b * NH + h;
                    *(bf16x8*)&qk_dst[bh * BH_STRIDE + (size_t)(t * 16 + m) * HD + j] = v;
                }
            }
        } else {
            const int m = t * 16 + lg * 4;
#pragma unroll
            for (int i = 0; i < 3; ++i) {
                int j2 = (wp * 3 + i) * 16 + lr;
                int h = j2 >> 5, j = j2 & 31;
                size_t bh = (size_t)b * NH + h;
                bf16x4 pk;
#pragma unroll
                for (int r = 0; r < 4; ++r) pk[r] = (__bf16)(acc[i][r] + bcol[i]);
                *(bf16x4*)&vtf[bh * BH_STRIDE + (size_t)j * SEQ + m] = pk;
            }
        }

        if (u < 17) {
            f32x4 v = nxt;
            bf16x4 pk;
            pk[0] = (__bf16)v[0]; pk[1] = (__bf16)v[1];
            pk[2] = (__bf16)v[2]; pk[3] = (__bf16)v[3];
            *(bf16x4*)&As[(u + 1) & 1][srow * 200 + sc4] = pk;
        }
    }
}

// ---------------------------------------------------------------------------
// Attention-only per (b,h) (R12-proven): K,V cooperatively staged, Q per-lane
// direct, bias L2, ONE barrier, R9 P2/softmax/P3. LDS 32768 B.
// ---------------------------------------------------------------------------
__global__ __launch_bounds__(576, 2) void k_attn3(char* __restrict__ ws) {
    const __bf16* bmB = (const __bf16*)(ws + WS_BM);
    const __bf16* qf  = (const __bf16*)(ws + WS_QF);
    const __bf16* kf  = (const __bf16*)(ws + WS_KF);
    const __bf16* vtf = (const __bf16*)(ws + WS_VT);
    __bf16* opre = (__bf16*)(ws + WS_QF);   // alias: own slice, read-then-write

    __shared__ char smem[32768];
    __bf16* Ks  = (__bf16*)smem;             // [144][40]  11520 B
    __bf16* Vt  = (__bf16*)(smem + 11520);   // [32][152]   9728 B
    __bf16* Pws = (__bf16*)(smem + 21248);   // 9 x [16][40] wave-private

    const int bx = blockIdx.x;               // 6144 = 6 h-groups x 1024 b
    const int h  = bx >> 10;
    const int b  = bx & 1023;
    const size_t bh = (size_t)(b * NH + h);

    const int tid  = threadIdx.x;
    const int w    = tid >> 6;
    const int lane = tid & 63;
    const int lr   = lane & 15;
    const int lg   = lane >> 4;
    const int m0   = w * 16;
    const f32x4 zf = {0.f, 0.f, 0.f, 0.f};
    const bf16x8 zb = {(__bf16)0.f,(__bf16)0.f,(__bf16)0.f,(__bf16)0.f,
                       (__bf16)0.f,(__bf16)0.f,(__bf16)0.f,(__bf16)0.f};

    // ---- issue all global loads up front
    bf16x8 kch = *(const bf16x8*)(kf  + bh * BH_STRIDE + (size_t)tid * 8);
    bf16x8 vch = *(const bf16x8*)(vtf + bh * BH_STRIDE + (size_t)tid * 8);
    bf16x8 qF  = *(const bf16x8*)(qf  + bh * BH_STRIDE + (size_t)(m0 + lr) * HD + lg * 8);
    bf16x4 bb[9];
    {
        const __bf16* bmh = bmB + h * 20736 + (m0 + lr) * SEQ;
#pragma unroll
        for (int i = 0; i < 9; ++i) bb[i] = *(const bf16x4*)&bmh[i * 16 + lg * 4];
    }

    // ---- stage to LDS
    *(bf16x8*)&Ks[(tid >> 2) * 40 + (tid & 3) * 8] = kch;
    {
        int vr = tid / 18, vc = tid % 18;
        *(bf16x8*)&Vt[vr * 152 + vc * 8] = vch;
    }
    lds_barrier();   // the ONE barrier

    // ---- P2: S^T = mfma(K,Q); +bias; in-register softmax
    f32x4 st[9];
#pragma unroll
    for (int i = 0; i < 9; ++i) {
        bf16x8 aF = *(bf16x8*)&Ks[(i * 16 + lr) * 40 + lg * 8];
        st[i] = __builtin_amdgcn_mfma_f32_16x16x32_bf16(aF, qF, zf, 0, 0, 0);
    }
    float mx = -3.0e38f;
#pragma unroll
    for (int i = 0; i < 9; ++i)
#pragma unroll
        for (int r = 0; r < 4; ++r) {
            st[i][r] += (float)bb[i][r];
            mx = fmaxf(mx, st[i][r]);
        }
    mx = fmaxf(mx, __shfl_xor(mx, 16));
    mx = fmaxf(mx, __shfl_xor(mx, 32));
    float sum = 0.f;
#pragma unroll
    for (int i = 0; i < 9; ++i)
#pragma unroll
        for (int r = 0; r < 4; ++r) {
            float e = __expf(st[i][r] - mx);
            st[i][r] = e;
            sum += e;
        }
    sum += __shfl_xor(sum, 16);
    sum += __shfl_xor(sum, 32);
    float inv = 1.f / sum;
#pragma unroll
    for (int i = 0; i < 9; ++i)
#pragma unroll
        for (int r = 0; r < 4; ++r) st[i][r] *= inv;

    // ---- P3: O = P @ V via per-wave P scratch
    __bf16* Pw = Pws + w * 640;    // [16][40]
    f32x4 o0 = zf, o1 = zf;
#pragma unroll
    for (int s = 0; s < 4; ++s) {
#pragma unroll
        for (int d = 0; d < 2; ++d) {
            int ii = 2 * s + d;
            bf16x4 pk;
#pragma unroll
            for (int r = 0; r < 4; ++r) pk[r] = (__bf16)st[ii][r];
            *(bf16x4*)&Pw[lr * 40 + d * 16 + lg * 4] = pk;
        }
        bf16x8 aP  = *(bf16x8*)&Pw[lr * 40 + lg * 8];
        bf16x8 v0F = *(bf16x8*)&Vt[lr * 152 + s * 32 + lg * 8];
        bf16x8 v1F = *(bf16x8*)&Vt[(16 + lr) * 152 + s * 32 + lg * 8];
        o0 = __builtin_amdgcn_mfma_f32_16x16x32_bf16(aP, v0F, o0, 0, 0, 0);
        o1 = __builtin_amdgcn_mfma_f32_16x16x32_bf16(aP, v1F, o1, 0, 0, 0);
    }
    {   // tail keys 128..143: lanes lg>=2 supply zeros
        bf16x4 pk;
#pragma unroll
        for (int r = 0; r < 4; ++r) pk[r] = (__bf16)st[8][r];
        *(bf16x4*)&Pw[lr * 40 + lg * 4] = pk;
        bf16x8 aP = zb, v0F = zb, v1F = zb;
        if (lg < 2) {
            aP  = *(bf16x8*)&Pw[lr * 40 + lg * 8];
            v0F = *(bf16x8*)&Vt[lr * 152 + 128 + lg * 8];
            v1F = *(bf16x8*)&Vt[(16 + lr) * 152 + 128 + lg * 8];
        }
        o0 = __builtin_amdgcn_mfma_f32_16x16x32_bf16(aP, v0F, o0, 0, 0, 0);
        o1 = __builtin_amdgcn_mfma_f32_16x16x32_bf16(aP, v1F, o1, 0, 0, 0);
    }

    // ---- O restage (coalesce) + store to opre (h-major, aliases own q slice)
#pragma unroll
    for (int r = 0; r < 4; ++r) {
        Pw[(lg * 4 + r) * 40 + lr]      = (__bf16)o0[r];
        Pw[(lg * 4 + r) * 40 + 16 + lr] = (__bf16)o1[r];
    }
    {
        int row = lane >> 2, c = lane & 3;
        bf16x8 ov = *(bf16x8*)&Pw[row * 40 + c * 8];
        *(bf16x8*)&opre[bh * BH_STRIDE + (size_t)(m0 + row) * HD + c * 8] = ov;
    }
}

// ---------------------------------------------------------------------------
// Out-projection (R12-proven): register-B, h-major gather, dbuf staging.
// ---------------------------------------------------------------------------
__global__ __launch_bounds__(256, 3) void k_proj(
        const char* __restrict__ ws, const float* __restrict__ b2,
        float* __restrict__ out) {
    const __bf16* opre = (const __bf16*)(ws + WS_QF);
    const __bf16* w2t  = (const __bf16*)(ws + WS_W2T);
    __shared__ __bf16 As[2][16 * 200];

    const int tid = threadIdx.x;
    const int w = tid >> 6, lr = tid & 15, lg = (tid & 63) >> 4;
    const int b = blockIdx.x;
    const f32x4 zf = {0.f, 0.f, 0.f, 0.f};

    bf16x8 bW[3][6];
    float bcol[3];
#pragma unroll
    for (int i = 0; i < 3; ++i) {
        int col = (w * 3 + i) * 16 + lr;
        bcol[i] = b2[col];
#pragma unroll
        for (int kk = 0; kk < 6; ++kk)
            bW[i][kk] = *(const bf16x8*)(w2t + (col * 192 + kk * 32 + lg * 8));
    }

    auto src_of = [&](int t, int c) -> const __bf16* {
        int lrow = c / 24, c8 = c % 24;
        int h = c8 >> 2, col32 = (c8 & 3) * 8;
        return opre + ((size_t)(b * NH + h)) * BH_STRIDE
                    + (size_t)(t * 16 + lrow) * HD + col32;
    };
    auto dst_of = [&](int buf, int c) -> __bf16* {
        int lrow = c / 24, c8 = c % 24;
        return &As[buf][lrow * 200 + c8 * 8];
    };

    {
        *(bf16x8*)dst_of(0, tid) = *(const bf16x8*)src_of(0, tid);
        if (tid < 128)
            *(bf16x8*)dst_of(0, tid + 256) = *(const bf16x8*)src_of(0, tid + 256);
    }

    for (int t = 0; t < 9; ++t) {
        bf16x8 n0, n1;
        if (t < 8) {
            n0 = *(const bf16x8*)src_of(t + 1, tid);
            if (tid < 128) n1 = *(const bf16x8*)src_of(t + 1, tid + 256);
        }
        lds_barrier();
        const __bf16* A = As[t & 1];
        f32x4 acc[3];
#pragma unroll
        for (int i = 0; i < 3; ++i) acc[i] = zf;
#pragma unroll
        for (int kk = 0; kk < 6; ++kk) {
            bf16x8 aF = *(const bf16x8*)&A[lr * 200 + kk * 32 + lg * 8];
#pragma unroll
            for (int i = 0; i < 3; ++i)
                acc[i] = __builtin_amdgcn_mfma_f32_16x16x32_bf16(aF, bW[i][kk], acc[i], 0, 0, 0);
        }
        size_t row0 = (size_t)b * SEQ + t * 16;
#pragma unroll
        for (int i = 0; i < 3; ++i) {
            int col = (w * 3 + i) * 16 + lr;
#pragma unroll
            for (int r = 0; r < 4; ++r)
                out[(row0 + lg * 4 + r) * DIM + col] = acc[i][r] + bcol[i];
        }
        if (t < 8) {
            *(bf16x8*)dst_of((t + 1) & 1, tid) = n0;
            if (tid < 128) *(bf16x8*)dst_of((t + 1) & 1, tid + 256) = n1;
        }
    }
}

// ---------------------------------------------------------------------------
extern "C" void kernel_launch(void* const* d_in, const int* in_sizes, int n_in,
                              void* d_out, int out_size, void* d_ws, size_t ws_size,
                              hipStream_t stream) {
    const float* x    = (const float*)d_in[0];
    const float* w1   = (const float*)d_in[1];
    const float* b1   = (const float*)d_in[2];
    const float* w2   = (const float*)d_in[3];
    const float* b2   = (const float*)d_in[4];
    const float* bt   = (const float*)d_in[5];
    const int*   pidx = (const int*)d_in[6];
    const int*   mask = (const int*)d_in[7];
    float* out = (float*)d_out;
    char*  ws  = (char*)d_ws;

    k_prep<<<658, 256, 0, stream>>>(w1, w2, b1, bt, pidx, mask, ws);
    k_qkv<<<BATCH / 2, 768, 0, stream>>>(x, ws);
    k_attn3<<<BATCH * NH, 576, 0, stream>>>(ws);
    k_proj<<<BATCH, 256, 0, stream>>>(ws, b2, out);
}

// Round 21
// 167.168 us; speedup vs baseline: 2.4254x; 1.0398x over previous
//
#include <hip/hip_runtime.h>

#define BATCH 1024
#define SEQ   144
#define DIM   192
#define NH    6
#define HD    32
#define SCALE 0.17677669529663687f   // 1/sqrt(32)

typedef __bf16 bf16x8 __attribute__((ext_vector_type(8)));
typedef __bf16 bf16x4 __attribute__((ext_vector_type(4)));
typedef float  f32x4  __attribute__((ext_vector_type(4)));

// LDS-only barrier (proven R9): orders ds_write->ds_read without draining vmcnt.
__device__ __forceinline__ void lds_barrier() {
    __builtin_amdgcn_sched_barrier(0);
    asm volatile("s_waitcnt lgkmcnt(0)" ::: "memory");
    __builtin_amdgcn_s_barrier();
    __builtin_amdgcn_sched_barrier(0);
}

// ---- workspace layout (bytes) ----
#define WS_W1T   0          // bf16 [576][192]  w1t[c][k] = w1[k][c] (*SCALE for c<192)
#define WS_W2T   221184     // bf16 [192][192]  w2t[n][k] = w2[k][n]
#define WS_B1S   294912     // f32  [576]       b1 (*SCALE for c<192)
#define WS_BM    297216     // bf16 [6][144][144]  bm[h][query][key] = bias + mask
#define WS_QF    546048     // bf16 [1024*6][144][32]  q ; aliased as opre after read
#define WS_KF    57169152   // bf16 [1024*6][144][32]  k
#define WS_VT    113792256  // bf16 [1024*6][32][144]  v^T
// total need 170415360 B (confirmed available in round 6)

#define BH_STRIDE 4608      // 144*32 elems per (b,h)

// ---------------------------------------------------------------------------
__global__ __launch_bounds__(256) void k_prep(
        const float* __restrict__ w1, const float* __restrict__ w2,
        const float* __restrict__ b1, const float* __restrict__ bt,
        const int* __restrict__ pidx, const int* __restrict__ mask,
        char* __restrict__ ws) {
    __bf16* w1t = (__bf16*)(ws + WS_W1T);
    __bf16* w2t = (__bf16*)(ws + WS_W2T);
    float*  b1s = (float*)(ws + WS_B1S);
    __bf16* bm  = (__bf16*)(ws + WS_BM);
    const int blk = blockIdx.x, t = threadIdx.x;
    if (blk < 432) {
        int idx = blk * 256 + t;
        int k = idx / 576, c = idx % 576;
        float v = w1[idx] * (c < 192 ? SCALE : 1.0f);
        w1t[c * 192 + k] = (__bf16)v;
    } else if (blk < 576) {
        int idx = (blk - 432) * 256 + t;
        int k = idx / 192, n = idx % 192;
        w2t[n * 192 + k] = (__bf16)w2[idx];
    } else if (blk < 657) {
        int idx = (blk - 576) * 256 + t;   // idx = query*144 + key
        int p = pidx[idx];
        float add = (mask[idx] == 0) ? -1e9f : 0.0f;
#pragma unroll
        for (int h = 0; h < NH; ++h)
            bm[h * 20736 + idx] = (__bf16)(bt[p * NH + h] + add);
    } else {
        for (int c = t; c < 576; c += 256)
            b1s[c] = b1[c] * (c < 192 ? SCALE : 1.0f);
    }
}

// ---------------------------------------------------------------------------
// QKV GEMM, TRIO-MERGED + 4-BATCH AMORTIZED: one 768-thread block handles
// FOUR b's (grid 256 = 1 block/CU, tail-free). Wave w: group cg=w/4
// (0=q,1=k,2=v), 48-col slice (w%4)*48; bW/bcol loaded ONCE per block
// (amortized over 36 tiles). Flattened 36-tile loop; dbuf staging pipelines
// seamlessly across b boundaries. LDS 27136 B; __launch_bounds__(768)
// (R19-proven, VGPR ~72).
// ---------------------------------------------------------------------------
__global__ __launch_bounds__(768) void k_qkv(
        const float* __restrict__ x, char* __restrict__ ws) {
    const __bf16* w1t = (const __bf16*)(ws + WS_W1T);
    const float*  b1s = (const float*)(ws + WS_B1S);
    __bf16* qf  = (__bf16*)(ws + WS_QF);
    __bf16* kf  = (__bf16*)(ws + WS_KF);
    __bf16* vtf = (__bf16*)(ws + WS_VT);

    __shared__ __bf16 As[2][16 * 200];      // 12800 B
    __shared__ __bf16 Stg[8][16 * 56];      // 14336 B: q/k waves' restage

    const int tid  = threadIdx.x;
    const int w    = tid >> 6;              // 0..11
    const int lane = tid & 63;
    const int lr   = lane & 15;
    const int lg   = lane >> 4;
    const int cg   = w >> 2;                // 0=q, 1=k, 2=v
    const int wp   = w & 3;                 // wave-in-group: 48-col slice
    const int b0   = blockIdx.x * 4;
    const f32x4 zf = {0.f, 0.f, 0.f, 0.f};

    // persistent B-frags + bias for this wave's 48 cols (loaded once / 4 b's)
    bf16x8 bW[3][6];
    float bcol[3];
#pragma unroll
    for (int i = 0; i < 3; ++i) {
        int col = cg * 192 + (wp * 3 + i) * 16 + lr;
        bcol[i] = b1s[col];
#pragma unroll
        for (int kk = 0; kk < 6; ++kk)
            bW[i][kk] = *(const bf16x8*)(w1t + (col * 192 + kk * 32 + lg * 8));
    }

    __bf16* qk_dst = (cg == 0) ? qf : kf;
    __bf16* stg = (cg < 2) ? Stg[w] : nullptr;

    const int srow = tid / 48, sc4 = (tid % 48) * 4;  // staging chunk coords

    // stage tile (b, t) into buf (1 f32x4 chunk per thread)
    auto stage_to = [&](int bb, int t, int buf) {
        const float* src = x + ((size_t)bb * SEQ + t * 16) * DIM;
        f32x4 v = *(const f32x4*)&src[srow * DIM + sc4];
        bf16x4 pk;
        pk[0] = (__bf16)v[0]; pk[1] = (__bf16)v[1];
        pk[2] = (__bf16)v[2]; pk[3] = (__bf16)v[3];
        *(bf16x4*)&As[buf][srow * 200 + sc4] = pk;
    };

    stage_to(b0, 0, 0);

    for (int u = 0; u < 36; ++u) {
        const int b = b0 + (u / 9);
        const int t = u % 9;

        // prefetch next unit's tile into regs
        f32x4 nxt;
        if (u < 35) {
            const int nb = b0 + ((u + 1) / 9);
            const int nt = (u + 1) % 9;
            const float* src = x + ((size_t)nb * SEQ + nt * 16) * DIM;
            nxt = *(const f32x4*)&src[srow * DIM + sc4];
        }
        lds_barrier();
        const __bf16* A = As[u & 1];
        f32x4 acc[3];
#pragma unroll
        for (int i = 0; i < 3; ++i) acc[i] = zf;
#pragma unroll
        for (int kk = 0; kk < 6; ++kk) {
            bf16x8 aF = *(const bf16x8*)&A[lr * 200 + kk * 32 + lg * 8];
#pragma unroll
            for (int i = 0; i < 3; ++i)
                acc[i] = __builtin_amdgcn_mfma_f32_16x16x32_bf16(aF, bW[i][kk], acc[i], 0, 0, 0);
        }

        // ---- epilogue
        if (cg < 2) {
            // restage to wave-private LDS [16 m][56] (+bias, bf16)
#pragma unroll
            for (int i = 0; i < 3; ++i)
#pragma unroll
                for (int r = 0; r < 4; ++r)
                    stg[(lg * 4 + r) * 56 + i * 16 + lr] = (__bf16)(acc[i][r] + bcol[i]);
            // wave-internal readback (same-wave DS ordering) + 16B stores
            // chunk c in [0,96): m=c/6, c8=c%6 ; dst j2 = wp*48 + c8*8
#pragma unroll
            for (int rep = 0; rep < 2; ++rep) {
                int c = lane + rep * 64;
                if (rep == 0 || lane < 32) {
                    int m = c / 6, c8 = c % 6;
                    bf16x8 v = *(bf16x8*)&stg[m * 56 + c8 * 8];
                    int j2 = wp * 48 + c8 * 8;
                    int h = j2 >> 5, j = j2 & 31;
                    size_t bh = (size_t)b * NH + h;
                    *(bf16x8*)&qk_dst[bh * BH_STRIDE + (size_t)(t * 16 + m) * HD + j] = v;
                }
            }
        } else {
            const int m = t * 16 + lg * 4;
#pragma unroll
            for (int i = 0; i < 3; ++i) {
                int j2 = (wp * 3 + i) * 16 + lr;
                int h = j2 >> 5, j = j2 & 31;
                size_t bh = (size_t)b * NH + h;
                bf16x4 pk;
#pragma unroll
                for (int r = 0; r < 4; ++r) pk[r] = (__bf16)(acc[i][r] + bcol[i]);
                *(bf16x4*)&vtf[bh * BH_STRIDE + (size_t)j * SEQ + m] = pk;
            }
        }

        if (u < 35) {
            f32x4 v = nxt;
            bf16x4 pk;
            pk[0] = (__bf16)v[0]; pk[1] = (__bf16)v[1];
            pk[2] = (__bf16)v[2]; pk[3] = (__bf16)v[3];
            *(bf16x4*)&As[(u + 1) & 1][srow * 200 + sc4] = pk;
        }
    }
}

// ---------------------------------------------------------------------------
// Attention-only per (b,h) (R12-proven): K,V cooperatively staged, Q per-lane
// direct, bias L2, ONE barrier, R9 P2/softmax/P3. LDS 32768 B.
// ---------------------------------------------------------------------------
__global__ __launch_bounds__(576, 2) void k_attn3(char* __restrict__ ws) {
    const __bf16* bmB = (const __bf16*)(ws + WS_BM);
    const __bf16* qf  = (const __bf16*)(ws + WS_QF);
    const __bf16* kf  = (const __bf16*)(ws + WS_KF);
    const __bf16* vtf = (const __bf16*)(ws + WS_VT);
    __bf16* opre = (__bf16*)(ws + WS_QF);   // alias: own slice, read-then-write

    __shared__ char smem[32768];
    __bf16* Ks  = (__bf16*)smem;             // [144][40]  11520 B
    __bf16* Vt  = (__bf16*)(smem + 11520);   // [32][152]   9728 B
    __bf16* Pws = (__bf16*)(smem + 21248);   // 9 x [16][40] wave-private

    const int bx = blockIdx.x;               // 6144 = 6 h-groups x 1024 b
    const int h  = bx >> 10;
    const int b  = bx & 1023;
    const size_t bh = (size_t)(b * NH + h);

    const int tid  = threadIdx.x;
    const int w    = tid >> 6;
    const int lane = tid & 63;
    const int lr   = lane & 15;
    const int lg   = lane >> 4;
    const int m0   = w * 16;
    const f32x4 zf = {0.f, 0.f, 0.f, 0.f};
    const bf16x8 zb = {(__bf16)0.f,(__bf16)0.f,(__bf16)0.f,(__bf16)0.f,
                       (__bf16)0.f,(__bf16)0.f,(__bf16)0.f,(__bf16)0.f};

    // ---- issue all global loads up front
    bf16x8 kch = *(const bf16x8*)(kf  + bh * BH_STRIDE + (size_t)tid * 8);
    bf16x8 vch = *(const bf16x8*)(vtf + bh * BH_STRIDE + (size_t)tid * 8);
    bf16x8 qF  = *(const bf16x8*)(qf  + bh * BH_STRIDE + (size_t)(m0 + lr) * HD + lg * 8);
    bf16x4 bb[9];
    {
        const __bf16* bmh = bmB + h * 20736 + (m0 + lr) * SEQ;
#pragma unroll
        for (int i = 0; i < 9; ++i) bb[i] = *(const bf16x4*)&bmh[i * 16 + lg * 4];
    }

    // ---- stage to LDS
    *(bf16x8*)&Ks[(tid >> 2) * 40 + (tid & 3) * 8] = kch;
    {
        int vr = tid / 18, vc = tid % 18;
        *(bf16x8*)&Vt[vr * 152 + vc * 8] = vch;
    }
    lds_barrier();   // the ONE barrier

    // ---- P2: S^T = mfma(K,Q); +bias; in-register softmax
    f32x4 st[9];
#pragma unroll
    for (int i = 0; i < 9; ++i) {
        bf16x8 aF = *(bf16x8*)&Ks[(i * 16 + lr) * 40 + lg * 8];
        st[i] = __builtin_amdgcn_mfma_f32_16x16x32_bf16(aF, qF, zf, 0, 0, 0);
    }
    float mx = -3.0e38f;
#pragma unroll
    for (int i = 0; i < 9; ++i)
#pragma unroll
        for (int r = 0; r < 4; ++r) {
            st[i][r] += (float)bb[i][r];
            mx = fmaxf(mx, st[i][r]);
        }
    mx = fmaxf(mx, __shfl_xor(mx, 16));
    mx = fmaxf(mx, __shfl_xor(mx, 32));
    float sum = 0.f;
#pragma unroll
    for (int i = 0; i < 9; ++i)
#pragma unroll
        for (int r = 0; r < 4; ++r) {
            float e = __expf(st[i][r] - mx);
            st[i][r] = e;
            sum += e;
        }
    sum += __shfl_xor(sum, 16);
    sum += __shfl_xor(sum, 32);
    float inv = 1.f / sum;
#pragma unroll
    for (int i = 0; i < 9; ++i)
#pragma unroll
        for (int r = 0; r < 4; ++r) st[i][r] *= inv;

    // ---- P3: O = P @ V via per-wave P scratch
    __bf16* Pw = Pws + w * 640;    // [16][40]
    f32x4 o0 = zf, o1 = zf;
#pragma unroll
    for (int s = 0; s < 4; ++s) {
#pragma unroll
        for (int d = 0; d < 2; ++d) {
            int ii = 2 * s + d;
            bf16x4 pk;
#pragma unroll
            for (int r = 0; r < 4; ++r) pk[r] = (__bf16)st[ii][r];
            *(bf16x4*)&Pw[lr * 40 + d * 16 + lg * 4] = pk;
        }
        bf16x8 aP  = *(bf16x8*)&Pw[lr * 40 + lg * 8];
        bf16x8 v0F = *(bf16x8*)&Vt[lr * 152 + s * 32 + lg * 8];
        bf16x8 v1F = *(bf16x8*)&Vt[(16 + lr) * 152 + s * 32 + lg * 8];
        o0 = __builtin_amdgcn_mfma_f32_16x16x32_bf16(aP, v0F, o0, 0, 0, 0);
        o1 = __builtin_amdgcn_mfma_f32_16x16x32_bf16(aP, v1F, o1, 0, 0, 0);
    }
    {   // tail keys 128..143: lanes lg>=2 supply zeros
        bf16x4 pk;
#pragma unroll
        for (int r = 0; r < 4; ++r) pk[r] = (__bf16)st[8][r];
        *(bf16x4*)&Pw[lr * 40 + lg * 4] = pk;
        bf16x8 aP = zb, v0F = zb, v1F = zb;
        if (lg < 2) {
            aP  = *(bf16x8*)&Pw[lr * 40 + lg * 8];
            v0F = *(bf16x8*)&Vt[lr * 152 + 128 + lg * 8];
            v1F = *(bf16x8*)&Vt[(16 + lr) * 152 + 128 + lg * 8];
        }
        o0 = __builtin_amdgcn_mfma_f32_16x16x32_bf16(aP, v0F, o0, 0, 0, 0);
        o1 = __builtin_amdgcn_mfma_f32_16x16x32_bf16(aP, v1F, o1, 0, 0, 0);
    }

    // ---- O restage (coalesce) + store to opre (h-major, aliases own q slice)
#pragma unroll
    for (int r = 0; r < 4; ++r) {
        Pw[(lg * 4 + r) * 40 + lr]      = (__bf16)o0[r];
        Pw[(lg * 4 + r) * 40 + 16 + lr] = (__bf16)o1[r];
    }
    {
        int row = lane >> 2, c = lane & 3;
        bf16x8 ov = *(bf16x8*)&Pw[row * 40 + c * 8];
        *(bf16x8*)&opre[bh * BH_STRIDE + (size_t)(m0 + row) * HD + c * 8] = ov;
    }
}

// ---------------------------------------------------------------------------
// Out-projection (R12-proven): register-B, h-major gather, dbuf staging.
// ---------------------------------------------------------------------------
__global__ __launch_bounds__(256, 3) void k_proj(
        const char* __restrict__ ws, const float* __restrict__ b2,
        float* __restrict__ out) {
    const __bf16* opre = (const __bf16*)(ws + WS_QF);
    const __bf16* w2t  = (const __bf16*)(ws + WS_W2T);
    __shared__ __bf16 As[2][16 * 200];

    const int tid = threadIdx.x;
    const int w = tid >> 6, lr = tid & 15, lg = (tid & 63) >> 4;
    const int b = blockIdx.x;
    const f32x4 zf = {0.f, 0.f, 0.f, 0.f};

    bf16x8 bW[3][6];
    float bcol[3];
#pragma unroll
    for (int i = 0; i < 3; ++i) {
        int col = (w * 3 + i) * 16 + lr;
        bcol[i] = b2[col];
#pragma unroll
        for (int kk = 0; kk < 6; ++kk)
            bW[i][kk] = *(const bf16x8*)(w2t + (col * 192 + kk * 32 + lg * 8));
    }

    auto src_of = [&](int t, int c) -> const __bf16* {
        int lrow = c / 24, c8 = c % 24;
        int h = c8 >> 2, col32 = (c8 & 3) * 8;
        return opre + ((size_t)(b * NH + h)) * BH_STRIDE
                    + (size_t)(t * 16 + lrow) * HD + col32;
    };
    auto dst_of = [&](int buf, int c) -> __bf16* {
        int lrow = c / 24, c8 = c % 24;
        return &As[buf][lrow * 200 + c8 * 8];
    };

    {
        *(bf16x8*)dst_of(0, tid) = *(const bf16x8*)src_of(0, tid);
        if (tid < 128)
            *(bf16x8*)dst_of(0, tid + 256) = *(const bf16x8*)src_of(0, tid + 256);
    }

    for (int t = 0; t < 9; ++t) {
        bf16x8 n0, n1;
        if (t < 8) {
            n0 = *(const bf16x8*)src_of(t + 1, tid);
            if (tid < 128) n1 = *(const bf16x8*)src_of(t + 1, tid + 256);
        }
        lds_barrier();
        const __bf16* A = As[t & 1];
        f32x4 acc[3];
#pragma unroll
        for (int i = 0; i < 3; ++i) acc[i] = zf;
#pragma unroll
        for (int kk = 0; kk < 6; ++kk) {
            bf16x8 aF = *(const bf16x8*)&A[lr * 200 + kk * 32 + lg * 8];
#pragma unroll
            for (int i = 0; i < 3; ++i)
                acc[i] = __builtin_amdgcn_mfma_f32_16x16x32_bf16(aF, bW[i][kk], acc[i], 0, 0, 0);
        }
        size_t row0 = (size_t)b * SEQ + t * 16;
#pragma unroll
        for (int i = 0; i < 3; ++i) {
            int col = (w * 3 + i) * 16 + lr;
#pragma unroll
            for (int r = 0; r < 4; ++r)
                out[(row0 + lg * 4 + r) * DIM + col] = acc[i][r] + bcol[i];
        }
        if (t < 8) {
            *(bf16x8*)dst_of((t + 1) & 1, tid) = n0;
            if (tid < 128) *(bf16x8*)dst_of((t + 1) & 1, tid + 256) = n1;
        }
    }
}

// ---------------------------------------------------------------------------
extern "C" void kernel_launch(void* const* d_in, const int* in_sizes, int n_in,
                              void* d_out, int out_size, void* d_ws, size_t ws_size,
                              hipStream_t stream) {
    const float* x    = (const float*)d_in[0];
    const float* w1   = (const float*)d_in[1];
    const float* b1   = (const float*)d_in[2];
    const float* w2   = (const float*)d_in[3];
    const float* b2   = (const float*)d_in[4];
    const float* bt   = (const float*)d_in[5];
    const int*   pidx = (const int*)d_in[6];
    const int*   mask = (const int*)d_in[7];
    float* out = (float*)d_out;
    char*  ws  = (char*)d_ws;

    k_prep<<<658, 256, 0, stream>>>(w1, w2, b1, bt, pidx, mask, ws);
    k_qkv<<<BATCH / 4, 768, 0, stream>>>(x, ws);
    k_attn3<<<BATCH * NH, 576, 0, stream>>>(ws);
    k_proj<<<BATCH, 256, 0, stream>>>(ws, b2, out);
}